// Round 6
// baseline (192.066 us; speedup 1.0000x reference)
//
#include <hip/hip_runtime.h>
#include <math.h>

// LeNet-5 fused forward, G=4 images per 256-thread block, 2048 blocks, all-MFMA.
// Round 17: register prefetch to kill latency serialization (VGPR was 32 -> compiler
// held only ~2 loads in flight; every phase ate full L2/LDS latency per fragment):
//   - C: all 6 W3H weight fragment pairs hoisted to regs before the i-loop
//   - D: all 26 W5H fragments prefetched BEFORE the C epilogue (epilogue+barrier+A5
//     build hide L2 latency); all 13 A5 LDS fragments prefetched after barrier [6]
//   - E: 8 F6H fragments prefetched during D epilogue; A6 fragments after barrier
//   - F: rbfT staged to LDS (dead A5 region) -> tail reads LDS, not 21 serial L2 hits
// Layouts and math identical to round 16 (passing).
typedef _Float16 h16;
typedef h16  h8v __attribute__((ext_vector_type(8)));
typedef h16  h4v __attribute__((ext_vector_type(4)));
typedef h16  h2v __attribute__((ext_vector_type(2)));
typedef float f4v __attribute__((ext_vector_type(4)));
typedef unsigned int u32;

// ws float offsets
#define WS_B1   0       // 6 f32
#define WS_B3   8       // 16 f32
#define WS_KB1  24      // [16][48] f16 (C1 B^T, slot layout) = 768 h16
#define WS_W3H  408     // [6][16][48] f16 (C3 B^T, slot layout) = 4608 h16
#define WS_W5H  2712    // [13][128][32] f16 (C5 B^T, K-packed kg=i*26+r, r<25 valid) = 53248 h16
#define WS_F6H  29336   // [96][128] f16 (F6 B^T, pads 0) = 12288 h16
#define WS_RBFT 35480   // 840 f32: rbf transposed [10][84]

// LDS byte offsets (8 barriers)
#define L_B3    0       // 64B
#define L_C5B   64      // 480B (120 f32)
#define L_F6B   544     // 336B (84 f32)
#define L_S2H   880     // 13824B [4][6][16][18] h16 (dead after C)
#define L_A5    880     // 13568B [16][424] h16 (over dead S2H)
#define L_HB    880     // 5632B  [16][88] f32 (over dead A5)
#define L_RBF   6512    // 3360B 840 f32 rbfT staged (over dead A5, after HB)
#define L_XPAD  14704   // 5184B: 2 imgs x [36][36] h16 (dead after B)
#define L_S4    14704   // 5376B [4][16][42] h16 (over dead XPAD)
#define L_A6    14704   // 4352B [16][136] h16 (over dead S4)
#define L_GUARD 19888   // 192B zero guard (covers out-of-window slot reads)
#define LDS_TOTAL 20080

__device__ const unsigned char MASK16[16] = {7,14,28,56,49,35,15,30,60,57,51,39,27,54,45,63};

// 1.7159*tanh((2/3)x) = 1.7159 - 3.4318/(1 + e^{(4/3)x})
__device__ __forceinline__ float squash(float x) {
    float E = __expf(1.33333333f * x);
    return 1.7159f - 3.4318f * __builtin_amdgcn_rcpf(1.0f + E);
}

// slot c (0..47) -> window (u,v); u=-1 means zero slot
__device__ __forceinline__ void slot_to_uv(int c, int& u, int& v) {
    u = -1; v = 0;
    if (c < 32) {
        int q = c >> 3, j = c & 7;
        if (j < 6)       { u = q;     v = j; }
        else if (q == 2) { u = 4;     v = j - 6; }
        else if (q == 3) { u = 5;     v = j - 6; }
    } else {
        int cc = c - 32, q = cc >> 2, j = cc & 3;
        if (q == 0)      { u = 4;     v = 2 + j; }
        else if (q == 1) { u = 5;     v = 2 + j; }
    }
}

__global__ __launch_bounds__(256) void prep_kernel(
    const float* __restrict__ c1_w, const float* __restrict__ c1_b,
    const float* __restrict__ s2_w, const float* __restrict__ s2_b,
    const float* __restrict__ c3_w, const float* __restrict__ c3_b,
    const float* __restrict__ s4_w, const float* __restrict__ s4_b,
    const float* __restrict__ c5_w, const float* __restrict__ f6_w,
    const float* __restrict__ rbf_w,
    float* __restrict__ ws)
{
    const int gid = blockIdx.x * 256 + threadIdx.x;
    const int gstr = gridDim.x * 256;
    if (gid < 6)  ws[WS_B1 + gid] = s2_w[gid] * c1_b[gid] + s2_b[gid];
    if (gid < 16) ws[WS_B3 + gid] = s4_w[gid] * c3_b[gid] + s4_b[gid];
    // KB1: [16 n][48 slots] B^T for C1+S2 folded conv
    h16* KB1 = (h16*)(ws + WS_KB1);
    for (int idx = gid; idx < 768; idx += gstr) {
        int n = idx / 48, c = idx - n * 48;
        int u, v; slot_to_uv(c, u, v);
        float val = 0.f;
        if (n < 6 && u >= 0) {
            float s = 0.f;
            #pragma unroll
            for (int dy = 0; dy < 2; ++dy)
                #pragma unroll
                for (int dx = 0; dx < 2; ++dx) {
                    int ky = u - dy, kx = v - dx;
                    if (ky >= 0 && ky < 5 && kx >= 0 && kx < 5)
                        s += c1_w[(n * 5 + ky) * 5 + kx];
                }
            val = 0.25f * s * s2_w[n];
        }
        KB1[idx] = (h16)val;
    }
    // W3H: [6 i][16 n][48 slots]
    h16* W3H = (h16*)(ws + WS_W3H);
    for (int idx = gid; idx < 4608; idx += gstr) {
        int i = idx / 768, r = idx - i * 768;
        int n = r / 48, c = r - n * 48;
        int u, v; slot_to_uv(c, u, v);
        float val = 0.f;
        if (u >= 0) {
            float s = 0.f;
            #pragma unroll
            for (int dy = 0; dy < 2; ++dy)
                #pragma unroll
                for (int dx = 0; dx < 2; ++dx) {
                    int ky = u - dy, kx = v - dx;
                    if (ky >= 0 && ky < 5 && kx >= 0 && kx < 5)
                        s += c3_w[((n * 6 + i) * 5 + ky) * 5 + kx];
                }
            val = ((MASK16[n] >> i) & 1) ? 0.25f * s4_w[n] * s : 0.f;
        }
        W3H[idx] = (h16)val;
    }
    // C5 weights K-packed pitch 26: kg = kb*32+k; i = kg/26, r = kg%26; r<25 valid
    h16* W5H = (h16*)(ws + WS_W5H);
    for (int idx = gid; idx < 53248; idx += gstr) {
        int kb = idx >> 12, rr = idx & 4095;
        int n = rr >> 5, k = rr & 31;
        int kg = kb * 32 + k;
        int i = kg / 26, r = kg - i * 26;
        float val = (n < 120 && r < 25) ? c5_w[n * 400 + i * 25 + r] : 0.f;
        W5H[idx] = (h16)val;
    }
    h16* F6H = (h16*)(ws + WS_F6H);
    for (int idx = gid; idx < 12288; idx += gstr) {
        int n = idx >> 7, k = idx & 127;
        float val = (n < 84 && k < 120) ? f6_w[n * 120 + k] : 0.f;
        F6H[idx] = (h16)val;
    }
    for (int idx = gid; idx < 840; idx += gstr) {
        int k = idx / 10, c = idx - k * 10;
        ws[WS_RBFT + c * 84 + k] = rbf_w[idx];
    }
}

__global__ __launch_bounds__(256, 8) void lenet_kernel(
    const float* __restrict__ x,
    const float* __restrict__ c5_b, const float* __restrict__ f6_b,
    const float* __restrict__ ws,
    float* __restrict__ out)
{
    __shared__ __align__(16) char smem[LDS_TOTAL];
    float* s_b3  = (float*)(smem + L_B3);
    float* s_c5b = (float*)(smem + L_C5B);
    float* s_f6b = (float*)(smem + L_F6B);
    float* s_rbf = (float*)(smem + L_RBF);
    h16*  XPAD   = (h16*)(smem + L_XPAD);
    h16*  S2H    = (h16*)(smem + L_S2H);
    h16*  S4     = (h16*)(smem + L_S4);
    h16*  A5     = (h16*)(smem + L_A5);
    h16*  A6     = (h16*)(smem + L_A6);
    float* HB    = (float*)(smem + L_HB);

    const int tid  = threadIdx.x;
    const int wave = __builtin_amdgcn_readfirstlane(tid >> 6);
    const int lane = tid & 63;
    const int quad = lane >> 4;
    const int lr   = lane & 15;

    // ---- stage consts; zero guard; load B-frags for phase B once (6 VGPRs) ----
    if (tid < 16)  s_b3[tid] = ws[WS_B3 + tid];
    if (tid < 120) s_c5b[tid] = c5_b[tid];
    if (tid < 84)  s_f6b[tid] = f6_b[tid];
    if (tid < 48)  ((u32*)(smem + L_GUARD))[tid] = 0u;
    const float* xb = x + (size_t)blockIdx.x * 4096;
    const h16* KB1 = (const h16*)(ws + WS_KB1);
    h8v w1a = *(const h8v*)(KB1 + lr * 48 + quad * 8);
    h4v w1b = *(const h4v*)(KB1 + lr * 48 + 32 + quad * 4);
    float b1v = ws[WS_B1 + (lr < 6 ? lr : 0)];

    // phase A stage: load imgs (2s, 2s+1) into XPAD with replicate pad
    auto stageA = [&](int s) {
        #pragma unroll
        for (int k = 0; k < 2; ++k) {
            int idx = tid + k * 256;            // 0..511: interior 2x32x8 float4
            int im = idx >> 8;
            int r  = (idx >> 3) & 31;
            int c4 = idx & 7;
            float4 v = *(const float4*)(xb + (2 * s + im) * 1024 + r * 32 + c4 * 4);
            h2v p0; p0.x = (h16)v.x; p0.y = (h16)v.y;
            h2v p1; p1.x = (h16)v.z; p1.y = (h16)v.w;
            h16* d = XPAD + im * 1296 + (r + 2) * 36 + (4 * c4 + 2);
            *(h2v*)(d)     = p0;
            *(h2v*)(d + 2) = p1;
        }
        #pragma unroll
        for (int k = 0; k < 3; ++k) {
            int e = tid + k * 256;              // 544 halo cells (3 passes)
            if (e < 544) {
                int im = (e >= 272) ? 1 : 0;
                int h = e - 272 * im;
                int u, v;
                if (h < 144) { int q = h / 36; u = (q < 2) ? q : 32 + q; v = h - q * 36; }
                else { int g = h - 144; u = 2 + (g >> 2); int q = g & 3; v = (q < 2) ? q : 32 + q; }
                int sr = min(max(u - 2, 0), 31), sc = min(max(v - 2, 0), 31);
                XPAD[im * 1296 + u * 36 + v] = (h16)xb[(2 * s + im) * 1024 + sr * 32 + sc];
            }
        }
    };

    // phase B stage: C1+S2+act via MFMA im2col, slot-permuted reads (P = 18 dwords)
    auto stageB = [&](int s) {
        const h16* bp = XPAD + (wave >> 1) * 1296 + (wave & 1) * 576 + 2 * lr;
        h16* s2base = S2H + (s * 2 + (wave >> 1)) * 1728 + lr * 288 + (wave & 1) * 144 + quad * 4;
        #pragma unroll
        for (int tt = 0; tt < 8; ++tt) {
            const u32* bq = (const u32*)bp + quad * 18;
            union { u32 u[4]; h8v h; } av;
            av.u[0] = bq[0];  av.u[1] = bq[1];
            av.u[2] = bq[2];  av.u[3] = bq[36];
            f4v acc = {b1v, b1v, b1v, b1v};
            acc = __builtin_amdgcn_mfma_f32_16x16x32_f16(av.h, w1a, acc, 0, 0, 0);
            union { u32 u[2]; h4v h; } av2;
            av2.u[0] = bq[73]; av2.u[1] = bq[74];
            acc = __builtin_amdgcn_mfma_f32_16x16x16f16(av2.h, w1b, acc, 0, 0, 0);
            if (lr < 6) {
                h2v q0; q0.x = (h16)squash(acc[0]); q0.y = (h16)squash(acc[1]);
                h2v q1; q1.x = (h16)squash(acc[2]); q1.y = (h16)squash(acc[3]);
                *(h2v*)(s2base + tt * 18)     = q0;
                *(h2v*)(s2base + tt * 18 + 2) = q1;
            }
            bp += 72;
        }
    };

    stageA(0);
    __syncthreads();   // [1] XPAD(0,1) + consts + guard ready
    stageB(0);
    __syncthreads();   // [2] XPAD(0,1) reads done
    stageA(1);
    __syncthreads();   // [3] XPAD(2,3) ready
    stageB(1);

    // prefetch C's weight fragments (global, latency hidden by barrier [4])
    const h16* W3H = (const h16*)(ws + WS_W3H);
    h8v w3as[6]; h4v w3bs[6];
    #pragma unroll
    for (int i = 0; i < 6; ++i) {
        const h16* bbase = W3H + i * 768 + lr * 48;
        w3as[i] = *(const h8v*)(bbase + quad * 8);
        w3bs[i] = *(const h4v*)(bbase + 32 + quad * 4);
    }
    __syncthreads();   // [4] S2H ready; XPAD dead

    // ======== C: C3+S4 via MFMA, slot-permuted reads from S2H (P = 9 dwords) ========
    f4v cacc0, cacc1, cacc2;
    const bool w0 = (wave == 0);
    {
        int baseh0, baseh1, baseh2;
        {
            int m0 = wave * 16 + lr;
            int i0 = m0 / 36, p0 = m0 - i0 * 36;
            baseh0 = i0 * 1728 + (2 * (p0 / 6)) * 18 + 2 * (p0 % 6);
            int m1 = (wave + 4) * 16 + lr;
            int i1 = m1 / 36, p1 = m1 - i1 * 36;
            baseh1 = i1 * 1728 + (2 * (p1 / 6)) * 18 + 2 * (p1 % 6);
            int m2 = 128 + lr;   // Mt=8 (wave 0 only)
            int i2 = m2 / 36, p2 = m2 - i2 * 36;
            baseh2 = i2 * 1728 + (2 * (p2 / 6)) * 18 + 2 * (p2 % 6);
        }
        float b3v = s_b3[lr];
        f4v cinit = {b3v, b3v, b3v, b3v};
        cacc0 = cinit; cacc1 = cinit; cacc2 = cinit;
        #pragma unroll
        for (int i = 0; i < 6; ++i) {
            {
                const u32* cq = (const u32*)(S2H + baseh0 + i * 288) + quad * 9;
                union { u32 u[4]; h8v h; } av;
                av.u[0] = cq[0];  av.u[1] = cq[1];
                av.u[2] = cq[2];  av.u[3] = cq[18];
                cacc0 = __builtin_amdgcn_mfma_f32_16x16x32_f16(av.h, w3as[i], cacc0, 0, 0, 0);
                union { u32 u[2]; h4v h; } av2;
                av2.u[0] = cq[37]; av2.u[1] = cq[38];
                cacc0 = __builtin_amdgcn_mfma_f32_16x16x16f16(av2.h, w3bs[i], cacc0, 0, 0, 0);
            }
            {
                const u32* cq = (const u32*)(S2H + baseh1 + i * 288) + quad * 9;
                union { u32 u[4]; h8v h; } av;
                av.u[0] = cq[0];  av.u[1] = cq[1];
                av.u[2] = cq[2];  av.u[3] = cq[18];
                cacc1 = __builtin_amdgcn_mfma_f32_16x16x32_f16(av.h, w3as[i], cacc1, 0, 0, 0);
                union { u32 u[2]; h4v h; } av2;
                av2.u[0] = cq[37]; av2.u[1] = cq[38];
                cacc1 = __builtin_amdgcn_mfma_f32_16x16x16f16(av2.h, w3bs[i], cacc1, 0, 0, 0);
            }
            if (w0) {
                const u32* cq = (const u32*)(S2H + baseh2 + i * 288) + quad * 9;
                union { u32 u[4]; h8v h; } av;
                av.u[0] = cq[0];  av.u[1] = cq[1];
                av.u[2] = cq[2];  av.u[3] = cq[18];
                cacc2 = __builtin_amdgcn_mfma_f32_16x16x32_f16(av.h, w3as[i], cacc2, 0, 0, 0);
                union { u32 u[2]; h4v h; } av2;
                av2.u[0] = cq[37]; av2.u[1] = cq[38];
                cacc2 = __builtin_amdgcn_mfma_f32_16x16x16f16(av2.h, w3bs[i], cacc2, 0, 0, 0);
            }
        }
    }

    // prefetch D's W5H weight fragments NOW (L2 latency hidden by C epilogue +
    // barrier [5] + A5 build). 26 x b128 = 104 VGPR.
    const h16* W5H = (const h16*)(ws + WS_W5H);
    h8v bf0s[13], bf1s[13];
    #pragma unroll
    for (int i = 0; i < 13; ++i) {
        bf0s[i] = *(const h8v*)(W5H + i * 4096 + (wave * 32 + lr) * 32 + quad * 8);
        bf1s[i] = *(const h8v*)(W5H + i * 4096 + (wave * 32 + 16 + lr) * 32 + quad * 8);
    }

    // C epilogue: squash -> S4 (over dead XPAD)
    {
        #pragma unroll
        for (int r = 0; r < 4; ++r) {
            int m = wave * 16 + quad * 4 + r;
            int img = m / 36, pos = m - img * 36;
            S4[img * 672 + lr * 42 + pos] = (h16)squash(cacc0[r]);
        }
        #pragma unroll
        for (int r = 0; r < 4; ++r) {
            int m = (wave + 4) * 16 + quad * 4 + r;
            int img = m / 36, pos = m - img * 36;
            S4[img * 672 + lr * 42 + pos] = (h16)squash(cacc1[r]);
        }
        if (w0) {
            #pragma unroll
            for (int r = 0; r < 4; ++r) {
                int m = 128 + quad * 4 + r;
                int img = m / 36, pos = m - img * 36;
                S4[img * 672 + lr * 42 + pos] = (h16)squash(cacc2[r]);
            }
        }
    }
    __syncthreads();   // [5] S4 ready; all S2H reads done

    // ======== D: C5 via MFMA. GEMM [16 x 416] x [416 x 128], K-packed pitch 26 ========
    // build A5 [16][424] (over dead S2H): thread = (m, i); A5[m][i*26+k] = window val
    {
        int m = tid >> 4, i = tid & 15;
        int img = m >> 2, q = m & 3, qy = q >> 1, qx = q & 1;
        const h16* s4b = S4 + img * 672 + i * 42 + qy * 6 + qx;
        u32* dst = (u32*)(A5 + m * 424 + i * 26);
        #pragma unroll
        for (int w = 0; w < 12; ++w) {
            int k0 = 2 * w, k1 = 2 * w + 1;
            union { h2v h; u32 u; } p;
            p.h.x = s4b[(k0 / 5) * 6 + (k0 % 5)];
            p.h.y = s4b[(k1 / 5) * 6 + (k1 % 5)];
            dst[w] = p.u;
        }
        {
            union { h2v h; u32 u; } p;
            p.h.x = s4b[28];  // k=24 -> (4,4)
            p.h.y = (h16)0.f;
            dst[12] = p.u;
        }
    }
    __syncthreads();   // [6] A5 ready

    {
        // prefetch all A5 fragments (LDS latency pipelined), then register-only MFMA
        h8v af0s[13];
        #pragma unroll
        for (int i = 0; i < 13; ++i)
            af0s[i] = *(const h8v*)(A5 + lr * 424 + i * 32 + quad * 8);
        float c5b0 = s_c5b[wave * 32 + lr];
        float c5b1 = s_c5b[wave * 32 + 16 + lr];   // may over-read into F6B consts; discarded
        f4v dacc0 = {c5b0, c5b0, c5b0, c5b0};
        f4v dacc1 = {c5b1, c5b1, c5b1, c5b1};
        #pragma unroll
        for (int i = 0; i < 13; ++i) {
            dacc0 = __builtin_amdgcn_mfma_f32_16x16x32_f16(af0s[i], bf0s[i], dacc0, 0, 0, 0);
            dacc1 = __builtin_amdgcn_mfma_f32_16x16x32_f16(af0s[i], bf1s[i], dacc1, 0, 0, 0);
        }
        // zero pad cols 120..127 of A6 (over dead S4)
        if (tid < 64) {
            int m = tid >> 2, j = tid & 3;
            *(u32*)(A6 + m * 136 + 120 + 2 * j) = 0u;
        }
        // epilogue, reference reshape: row=img*4+(n/30), col=(n%30)*4+q
        {
            int n0 = wave * 32 + lr;
            if (n0 < 120) {
                int tt = n0 / 30, cb = (n0 - tt * 30) * 4;
                #pragma unroll
                for (int r = 0; r < 4; ++r) {
                    int m = quad * 4 + r;
                    A6[((m >> 2) * 4 + tt) * 136 + cb + (m & 3)] = (h16)dacc0[r];
                }
            }
            int n1 = wave * 32 + 16 + lr;
            if (n1 < 120) {
                int tt = n1 / 30, cb = (n1 - tt * 30) * 4;
                #pragma unroll
                for (int r = 0; r < 4; ++r) {
                    int m = quad * 4 + r;
                    A6[((m >> 2) * 4 + tt) * 136 + cb + (m & 3)] = (h16)dacc1[r];
                }
            }
        }
    }

    // prefetch E's F6H fragments (global) + rbfT into regs; latency hidden by barrier [7]
    const h16* F6H = (const h16*)(ws + WS_F6H);
    const int wv2 = (wave < 2) ? wave + 4 : wave;   // row stays < 96 for all waves
    h8v eb0s[4], eb1s[4];
    #pragma unroll
    for (int kc = 0; kc < 4; ++kc) {
        eb0s[kc] = *(const h8v*)(F6H + (wave * 16 + lr) * 128 + kc * 32 + quad * 8);
        eb1s[kc] = *(const h8v*)(F6H + (wv2 * 16 + lr) * 128 + kc * 32 + quad * 8);
    }
    float4 rv = {0.f, 0.f, 0.f, 0.f};
    if (tid < 210) rv = *(const float4*)(ws + WS_RBFT + tid * 4);
    __syncthreads();   // [7] A6 ready; all A5 reads done

    // stage rbfT to LDS (region dead after [7]; read after [8])
    if (tid < 210) *(float4*)(s_rbf + tid * 4) = rv;

    // ======== E: F6+act via MFMA. GEMM [16 x 128] x [128 x 96] ========
    {
        h8v a8s[4];
        #pragma unroll
        for (int kc = 0; kc < 4; ++kc)
            a8s[kc] = *(const h8v*)(A6 + lr * 136 + kc * 32 + quad * 8);
        float f60 = s_f6b[wave * 16 + lr];
        f4v eacc0 = {f60, f60, f60, f60};
        f4v eacc1 = {};
        const bool w2 = (wave < 2);
        if (w2) {
            int n1 = (wave + 4) * 16 + lr;
            float f61 = (n1 < 84) ? s_f6b[n1] : 0.f;
            eacc1[0] = f61; eacc1[1] = f61; eacc1[2] = f61; eacc1[3] = f61;
        }
        #pragma unroll
        for (int kc = 0; kc < 4; ++kc) {
            eacc0 = __builtin_amdgcn_mfma_f32_16x16x32_f16(a8s[kc], eb0s[kc], eacc0, 0, 0, 0);
            if (w2)
                eacc1 = __builtin_amdgcn_mfma_f32_16x16x32_f16(a8s[kc], eb1s[kc], eacc1, 0, 0, 0);
        }
        {
            int n = wave * 16 + lr;   // 0..63 < 84
            #pragma unroll
            for (int r = 0; r < 4; ++r) {
                int m = quad * 4 + r;
                HB[m * 88 + n] = squash(eacc0[r]);   // HB over dead A5
            }
        }
        if (w2) {
            int n = (wave + 4) * 16 + lr;  // 64..95
            if (n < 84) {
                #pragma unroll
                for (int r = 0; r < 4; ++r) {
                    int m = quad * 4 + r;
                    HB[m * 88 + n] = squash(eacc1[r]);
                }
            }
        }
    }
    __syncthreads();   // [8] HB + rbf ready

    // ======== F: RBF distances (VALU); prototypes from LDS ========
    if (tid < 160) {
        int m = tid / 10, cls = tid - m * 10;
        const float4* hr = (const float4*)(HB + m * 88);
        const float4* pr = (const float4*)(s_rbf + cls * 84);
        float a = 0.f;
        #pragma unroll
        for (int u = 0; u < 21; ++u) {
            float4 hv = hr[u], pv = pr[u];
            float dx = hv.x - pv.x, dy = hv.y - pv.y;
            float dz = hv.z - pv.z, dw = hv.w - pv.w;
            a += dx * dx + dy * dy + dz * dz + dw * dw;
        }
        out[(size_t)blockIdx.x * 160 + tid] = a;
    }
}

extern "C" void kernel_launch(void* const* d_in, const int* in_sizes, int n_in,
                              void* d_out, int out_size, void* d_ws, size_t ws_size,
                              hipStream_t stream) {
    (void)n_in; (void)out_size; (void)ws_size;
    const float* x     = (const float*)d_in[0];
    const float* c1_w  = (const float*)d_in[1];
    const float* c1_b  = (const float*)d_in[2];
    const float* s2_w  = (const float*)d_in[3];
    const float* s2_b  = (const float*)d_in[4];
    const float* c3_w  = (const float*)d_in[5];
    const float* c3_b  = (const float*)d_in[6];
    const float* s4_w  = (const float*)d_in[7];
    const float* s4_b  = (const float*)d_in[8];
    const float* c5_w  = (const float*)d_in[9];
    const float* c5_b  = (const float*)d_in[10];
    const float* f6_w  = (const float*)d_in[11];
    const float* f6_b  = (const float*)d_in[12];
    const float* rbf_w = (const float*)d_in[13];
    float* out = (float*)d_out;
    float* ws  = (float*)d_ws;

    const int B = in_sizes[0] / 1024;   // 8192

    prep_kernel<<<256, 256, 0, stream>>>(c1_w, c1_b, s2_w, s2_b, c3_w, c3_b,
                                         s4_w, s4_b, c5_w, f6_w, rbf_w, ws);
    lenet_kernel<<<B / 4, 256, 0, stream>>>(x, c5_b, f6_b, ws, out);
}

// Round 7
// 133.408 us; speedup vs baseline: 1.4397x; 1.4397x over previous
//
#include <hip/hip_runtime.h>
#include <math.h>

// LeNet-5 fused forward, G=4 images per 256-thread block, 2048 blocks, all-MFMA.
// Round 18: round-6 full prefetch spilled (64-VGPR cap at 8 blocks/CU; WRITE_SIZE
// 1280->181504 KB = scratch). Revert to round-5 structure + SPILL-SAFE depth-2 pipelines:
//   - D: rolling prefetch {bf0,bf1,af0} one iter ahead (24 VGPR in flight);
//        iter-0 weight loads issued before barrier [5] (L2 latency hidden by A5 build)
//   - E: depth-2 rotation for F6H/A6 fragments; iter-0 loads before barrier [7]
//   - F: rbfT staged to LDS via 4-VGPR bounce (dead-A5 region) -> tail reads LDS
// Phase C unchanged from round 5 (hoist would exceed the 64-VGPR phase peak).
typedef _Float16 h16;
typedef h16  h8v __attribute__((ext_vector_type(8)));
typedef h16  h4v __attribute__((ext_vector_type(4)));
typedef h16  h2v __attribute__((ext_vector_type(2)));
typedef float f4v __attribute__((ext_vector_type(4)));
typedef unsigned int u32;

// ws float offsets
#define WS_B1   0       // 6 f32
#define WS_B3   8       // 16 f32
#define WS_KB1  24      // [16][48] f16 (C1 B^T, slot layout) = 768 h16
#define WS_W3H  408     // [6][16][48] f16 (C3 B^T, slot layout) = 4608 h16
#define WS_W5H  2712    // [13][128][32] f16 (C5 B^T, K-packed kg=i*26+r, r<25 valid) = 53248 h16
#define WS_F6H  29336   // [96][128] f16 (F6 B^T, pads 0) = 12288 h16
#define WS_RBFT 35480   // 840 f32: rbf transposed [10][84]

// LDS byte offsets (8 barriers)
#define L_B3    0       // 64B
#define L_C5B   64      // 480B (120 f32)
#define L_F6B   544     // 336B (84 f32)
#define L_S2H   880     // 13824B [4][6][16][18] h16 (dead after C)
#define L_A5    880     // 13568B [16][424] h16 (over dead S2H)
#define L_HB    880     // 5632B  [16][88] f32 (over dead A5)
#define L_RBF   6512    // 3360B 840 f32 rbfT staged (over dead A5; written after [7])
#define L_XPAD  14704   // 5184B: 2 imgs x [36][36] h16 (dead after B)
#define L_S4    14704   // 5376B [4][16][42] h16 (over dead XPAD)
#define L_A6    14704   // 4352B [16][136] h16 (over dead S4)
#define L_GUARD 19888   // 192B zero guard (covers out-of-window slot reads)
#define LDS_TOTAL 20080

__device__ const unsigned char MASK16[16] = {7,14,28,56,49,35,15,30,60,57,51,39,27,54,45,63};

// 1.7159*tanh((2/3)x) = 1.7159 - 3.4318/(1 + e^{(4/3)x})
__device__ __forceinline__ float squash(float x) {
    float E = __expf(1.33333333f * x);
    return 1.7159f - 3.4318f * __builtin_amdgcn_rcpf(1.0f + E);
}

// slot c (0..47) -> window (u,v); u=-1 means zero slot
__device__ __forceinline__ void slot_to_uv(int c, int& u, int& v) {
    u = -1; v = 0;
    if (c < 32) {
        int q = c >> 3, j = c & 7;
        if (j < 6)       { u = q;     v = j; }
        else if (q == 2) { u = 4;     v = j - 6; }
        else if (q == 3) { u = 5;     v = j - 6; }
    } else {
        int cc = c - 32, q = cc >> 2, j = cc & 3;
        if (q == 0)      { u = 4;     v = 2 + j; }
        else if (q == 1) { u = 5;     v = 2 + j; }
    }
}

__global__ __launch_bounds__(256) void prep_kernel(
    const float* __restrict__ c1_w, const float* __restrict__ c1_b,
    const float* __restrict__ s2_w, const float* __restrict__ s2_b,
    const float* __restrict__ c3_w, const float* __restrict__ c3_b,
    const float* __restrict__ s4_w, const float* __restrict__ s4_b,
    const float* __restrict__ c5_w, const float* __restrict__ f6_w,
    const float* __restrict__ rbf_w,
    float* __restrict__ ws)
{
    const int gid = blockIdx.x * 256 + threadIdx.x;
    const int gstr = gridDim.x * 256;
    if (gid < 6)  ws[WS_B1 + gid] = s2_w[gid] * c1_b[gid] + s2_b[gid];
    if (gid < 16) ws[WS_B3 + gid] = s4_w[gid] * c3_b[gid] + s4_b[gid];
    h16* KB1 = (h16*)(ws + WS_KB1);
    for (int idx = gid; idx < 768; idx += gstr) {
        int n = idx / 48, c = idx - n * 48;
        int u, v; slot_to_uv(c, u, v);
        float val = 0.f;
        if (n < 6 && u >= 0) {
            float s = 0.f;
            #pragma unroll
            for (int dy = 0; dy < 2; ++dy)
                #pragma unroll
                for (int dx = 0; dx < 2; ++dx) {
                    int ky = u - dy, kx = v - dx;
                    if (ky >= 0 && ky < 5 && kx >= 0 && kx < 5)
                        s += c1_w[(n * 5 + ky) * 5 + kx];
                }
            val = 0.25f * s * s2_w[n];
        }
        KB1[idx] = (h16)val;
    }
    h16* W3H = (h16*)(ws + WS_W3H);
    for (int idx = gid; idx < 4608; idx += gstr) {
        int i = idx / 768, r = idx - i * 768;
        int n = r / 48, c = r - n * 48;
        int u, v; slot_to_uv(c, u, v);
        float val = 0.f;
        if (u >= 0) {
            float s = 0.f;
            #pragma unroll
            for (int dy = 0; dy < 2; ++dy)
                #pragma unroll
                for (int dx = 0; dx < 2; ++dx) {
                    int ky = u - dy, kx = v - dx;
                    if (ky >= 0 && ky < 5 && kx >= 0 && kx < 5)
                        s += c3_w[((n * 6 + i) * 5 + ky) * 5 + kx];
                }
            val = ((MASK16[n] >> i) & 1) ? 0.25f * s4_w[n] * s : 0.f;
        }
        W3H[idx] = (h16)val;
    }
    h16* W5H = (h16*)(ws + WS_W5H);
    for (int idx = gid; idx < 53248; idx += gstr) {
        int kb = idx >> 12, rr = idx & 4095;
        int n = rr >> 5, k = rr & 31;
        int kg = kb * 32 + k;
        int i = kg / 26, r = kg - i * 26;
        float val = (n < 120 && r < 25) ? c5_w[n * 400 + i * 25 + r] : 0.f;
        W5H[idx] = (h16)val;
    }
    h16* F6H = (h16*)(ws + WS_F6H);
    for (int idx = gid; idx < 12288; idx += gstr) {
        int n = idx >> 7, k = idx & 127;
        float val = (n < 84 && k < 120) ? f6_w[n * 120 + k] : 0.f;
        F6H[idx] = (h16)val;
    }
    for (int idx = gid; idx < 840; idx += gstr) {
        int k = idx / 10, c = idx - k * 10;
        ws[WS_RBFT + c * 84 + k] = rbf_w[idx];
    }
}

__global__ __launch_bounds__(256, 8) void lenet_kernel(
    const float* __restrict__ x,
    const float* __restrict__ c5_b, const float* __restrict__ f6_b,
    const float* __restrict__ ws,
    float* __restrict__ out)
{
    __shared__ __align__(16) char smem[LDS_TOTAL];
    float* s_b3  = (float*)(smem + L_B3);
    float* s_c5b = (float*)(smem + L_C5B);
    float* s_f6b = (float*)(smem + L_F6B);
    float* s_rbf = (float*)(smem + L_RBF);
    h16*  XPAD   = (h16*)(smem + L_XPAD);
    h16*  S2H    = (h16*)(smem + L_S2H);
    h16*  S4     = (h16*)(smem + L_S4);
    h16*  A5     = (h16*)(smem + L_A5);
    h16*  A6     = (h16*)(smem + L_A6);
    float* HB    = (float*)(smem + L_HB);

    const int tid  = threadIdx.x;
    const int wave = __builtin_amdgcn_readfirstlane(tid >> 6);
    const int lane = tid & 63;
    const int quad = lane >> 4;
    const int lr   = lane & 15;

    // ---- stage consts; zero guard; load B-frags for phase B once (6 VGPRs) ----
    if (tid < 16)  s_b3[tid] = ws[WS_B3 + tid];
    if (tid < 120) s_c5b[tid] = c5_b[tid];
    if (tid < 84)  s_f6b[tid] = f6_b[tid];
    if (tid < 48)  ((u32*)(smem + L_GUARD))[tid] = 0u;
    const float* xb = x + (size_t)blockIdx.x * 4096;
    const h16* KB1 = (const h16*)(ws + WS_KB1);
    h8v w1a = *(const h8v*)(KB1 + lr * 48 + quad * 8);
    h4v w1b = *(const h4v*)(KB1 + lr * 48 + 32 + quad * 4);
    float b1v = ws[WS_B1 + (lr < 6 ? lr : 0)];

    // phase A stage: load imgs (2s, 2s+1) into XPAD with replicate pad
    auto stageA = [&](int s) {
        #pragma unroll
        for (int k = 0; k < 2; ++k) {
            int idx = tid + k * 256;            // 0..511: interior 2x32x8 float4
            int im = idx >> 8;
            int r  = (idx >> 3) & 31;
            int c4 = idx & 7;
            float4 v = *(const float4*)(xb + (2 * s + im) * 1024 + r * 32 + c4 * 4);
            h2v p0; p0.x = (h16)v.x; p0.y = (h16)v.y;
            h2v p1; p1.x = (h16)v.z; p1.y = (h16)v.w;
            h16* d = XPAD + im * 1296 + (r + 2) * 36 + (4 * c4 + 2);
            *(h2v*)(d)     = p0;
            *(h2v*)(d + 2) = p1;
        }
        #pragma unroll
        for (int k = 0; k < 3; ++k) {
            int e = tid + k * 256;              // 544 halo cells (3 passes)
            if (e < 544) {
                int im = (e >= 272) ? 1 : 0;
                int h = e - 272 * im;
                int u, v;
                if (h < 144) { int q = h / 36; u = (q < 2) ? q : 32 + q; v = h - q * 36; }
                else { int g = h - 144; u = 2 + (g >> 2); int q = g & 3; v = (q < 2) ? q : 32 + q; }
                int sr = min(max(u - 2, 0), 31), sc = min(max(v - 2, 0), 31);
                XPAD[im * 1296 + u * 36 + v] = (h16)xb[(2 * s + im) * 1024 + sr * 32 + sc];
            }
        }
    };

    // phase B stage: C1+S2+act via MFMA im2col, slot-permuted reads (P = 18 dwords)
    auto stageB = [&](int s) {
        const h16* bp = XPAD + (wave >> 1) * 1296 + (wave & 1) * 576 + 2 * lr;
        h16* s2base = S2H + (s * 2 + (wave >> 1)) * 1728 + lr * 288 + (wave & 1) * 144 + quad * 4;
        #pragma unroll
        for (int tt = 0; tt < 8; ++tt) {
            const u32* bq = (const u32*)bp + quad * 18;
            union { u32 u[4]; h8v h; } av;
            av.u[0] = bq[0];  av.u[1] = bq[1];
            av.u[2] = bq[2];  av.u[3] = bq[36];
            f4v acc = {b1v, b1v, b1v, b1v};
            acc = __builtin_amdgcn_mfma_f32_16x16x32_f16(av.h, w1a, acc, 0, 0, 0);
            union { u32 u[2]; h4v h; } av2;
            av2.u[0] = bq[73]; av2.u[1] = bq[74];
            acc = __builtin_amdgcn_mfma_f32_16x16x16f16(av2.h, w1b, acc, 0, 0, 0);
            if (lr < 6) {
                h2v q0; q0.x = (h16)squash(acc[0]); q0.y = (h16)squash(acc[1]);
                h2v q1; q1.x = (h16)squash(acc[2]); q1.y = (h16)squash(acc[3]);
                *(h2v*)(s2base + tt * 18)     = q0;
                *(h2v*)(s2base + tt * 18 + 2) = q1;
            }
            bp += 72;
        }
    };

    stageA(0);
    __syncthreads();   // [1] XPAD(0,1) + consts + guard ready
    stageB(0);
    __syncthreads();   // [2] XPAD(0,1) reads done
    stageA(1);
    __syncthreads();   // [3] XPAD(2,3) ready
    stageB(1);
    __syncthreads();   // [4] S2H ready; XPAD dead

    // ======== C: C3+S4 via MFMA, slot-permuted reads from S2H (P = 9 dwords) ========
    f4v cacc0, cacc1, cacc2;
    const bool w0 = (wave == 0);
    {
        const h16* W3H = (const h16*)(ws + WS_W3H);
        int baseh0, baseh1, baseh2;
        {
            int m0 = wave * 16 + lr;
            int i0 = m0 / 36, p0 = m0 - i0 * 36;
            baseh0 = i0 * 1728 + (2 * (p0 / 6)) * 18 + 2 * (p0 % 6);
            int m1 = (wave + 4) * 16 + lr;
            int i1 = m1 / 36, p1 = m1 - i1 * 36;
            baseh1 = i1 * 1728 + (2 * (p1 / 6)) * 18 + 2 * (p1 % 6);
            int m2 = 128 + lr;   // Mt=8 (wave 0 only)
            int i2 = m2 / 36, p2 = m2 - i2 * 36;
            baseh2 = i2 * 1728 + (2 * (p2 / 6)) * 18 + 2 * (p2 % 6);
        }
        float b3v = s_b3[lr];
        f4v cinit = {b3v, b3v, b3v, b3v};
        cacc0 = cinit; cacc1 = cinit; cacc2 = cinit;
        #pragma unroll
        for (int i = 0; i < 6; ++i) {
            const h16* bbase = W3H + i * 768 + lr * 48;
            h8v w3a = *(const h8v*)(bbase + quad * 8);
            h4v w3b = *(const h4v*)(bbase + 32 + quad * 4);
            {
                const u32* cq = (const u32*)(S2H + baseh0 + i * 288) + quad * 9;
                union { u32 u[4]; h8v h; } av;
                av.u[0] = cq[0];  av.u[1] = cq[1];
                av.u[2] = cq[2];  av.u[3] = cq[18];
                cacc0 = __builtin_amdgcn_mfma_f32_16x16x32_f16(av.h, w3a, cacc0, 0, 0, 0);
                union { u32 u[2]; h4v h; } av2;
                av2.u[0] = cq[37]; av2.u[1] = cq[38];
                cacc0 = __builtin_amdgcn_mfma_f32_16x16x16f16(av2.h, w3b, cacc0, 0, 0, 0);
            }
            {
                const u32* cq = (const u32*)(S2H + baseh1 + i * 288) + quad * 9;
                union { u32 u[4]; h8v h; } av;
                av.u[0] = cq[0];  av.u[1] = cq[1];
                av.u[2] = cq[2];  av.u[3] = cq[18];
                cacc1 = __builtin_amdgcn_mfma_f32_16x16x32_f16(av.h, w3a, cacc1, 0, 0, 0);
                union { u32 u[2]; h4v h; } av2;
                av2.u[0] = cq[37]; av2.u[1] = cq[38];
                cacc1 = __builtin_amdgcn_mfma_f32_16x16x16f16(av2.h, w3b, cacc1, 0, 0, 0);
            }
            if (w0) {
                const u32* cq = (const u32*)(S2H + baseh2 + i * 288) + quad * 9;
                union { u32 u[4]; h8v h; } av;
                av.u[0] = cq[0];  av.u[1] = cq[1];
                av.u[2] = cq[2];  av.u[3] = cq[18];
                cacc2 = __builtin_amdgcn_mfma_f32_16x16x32_f16(av.h, w3a, cacc2, 0, 0, 0);
                union { u32 u[2]; h4v h; } av2;
                av2.u[0] = cq[37]; av2.u[1] = cq[38];
                cacc2 = __builtin_amdgcn_mfma_f32_16x16x16f16(av2.h, w3b, cacc2, 0, 0, 0);
            }
        }
    }

    // D iter-0 weight loads: global (L2), independent of LDS state. Issue NOW so
    // epilogue + barrier [5] + A5 build hide the latency. Only 8 VGPRs in flight.
    const h16* W5H = (const h16*)(ws + WS_W5H);
    h8v bf0c = *(const h8v*)(W5H + (wave * 32 + lr) * 32 + quad * 8);
    h8v bf1c = *(const h8v*)(W5H + (wave * 32 + 16 + lr) * 32 + quad * 8);

    // C epilogue: squash -> S4 (over dead XPAD)
    {
        #pragma unroll
        for (int r = 0; r < 4; ++r) {
            int m = wave * 16 + quad * 4 + r;
            int img = m / 36, pos = m - img * 36;
            S4[img * 672 + lr * 42 + pos] = (h16)squash(cacc0[r]);
        }
        #pragma unroll
        for (int r = 0; r < 4; ++r) {
            int m = (wave + 4) * 16 + quad * 4 + r;
            int img = m / 36, pos = m - img * 36;
            S4[img * 672 + lr * 42 + pos] = (h16)squash(cacc1[r]);
        }
        if (w0) {
            #pragma unroll
            for (int r = 0; r < 4; ++r) {
                int m = 128 + quad * 4 + r;
                int img = m / 36, pos = m - img * 36;
                S4[img * 672 + lr * 42 + pos] = (h16)squash(cacc2[r]);
            }
        }
    }
    __syncthreads();   // [5] S4 ready; all S2H reads done

    // ======== D: C5 via MFMA. GEMM [16 x 416] x [416 x 128], K-packed pitch 26 ========
    // build A5 [16][424] (over dead S2H): thread = (m, i); A5[m][i*26+k] = window val
    {
        int m = tid >> 4, i = tid & 15;
        int img = m >> 2, q = m & 3, qy = q >> 1, qx = q & 1;
        const h16* s4b = S4 + img * 672 + i * 42 + qy * 6 + qx;
        u32* dst = (u32*)(A5 + m * 424 + i * 26);
        #pragma unroll
        for (int w = 0; w < 12; ++w) {
            int k0 = 2 * w, k1 = 2 * w + 1;
            union { h2v h; u32 u; } p;
            p.h.x = s4b[(k0 / 5) * 6 + (k0 % 5)];
            p.h.y = s4b[(k1 / 5) * 6 + (k1 % 5)];
            dst[w] = p.u;
        }
        {
            union { h2v h; u32 u; } p;
            p.h.x = s4b[28];  // k=24 -> (4,4)
            p.h.y = (h16)0.f;
            dst[12] = p.u;
        }
    }
    __syncthreads();   // [6] A5 ready

    {
        // depth-2 rolling pipeline: prefetch iter i+1 while MFMA on iter i.
        h8v af0c = *(const h8v*)(A5 + lr * 424 + quad * 8);
        float c5b0 = s_c5b[wave * 32 + lr];
        float c5b1 = s_c5b[wave * 32 + 16 + lr];   // may over-read into F6B consts; discarded
        f4v dacc0 = {c5b0, c5b0, c5b0, c5b0};
        f4v dacc1 = {c5b1, c5b1, c5b1, c5b1};
        #pragma unroll
        for (int i = 0; i < 13; ++i) {
            h8v bf0n, bf1n, af0n;
            if (i < 12) {
                bf0n = *(const h8v*)(W5H + (i + 1) * 4096 + (wave * 32 + lr) * 32 + quad * 8);
                bf1n = *(const h8v*)(W5H + (i + 1) * 4096 + (wave * 32 + 16 + lr) * 32 + quad * 8);
                af0n = *(const h8v*)(A5 + lr * 424 + (i + 1) * 32 + quad * 8);
            }
            dacc0 = __builtin_amdgcn_mfma_f32_16x16x32_f16(af0c, bf0c, dacc0, 0, 0, 0);
            dacc1 = __builtin_amdgcn_mfma_f32_16x16x32_f16(af0c, bf1c, dacc1, 0, 0, 0);
            if (i < 12) { bf0c = bf0n; bf1c = bf1n; af0c = af0n; }
        }
        // zero pad cols 120..127 of A6 (over dead S4)
        if (tid < 64) {
            int m = tid >> 2, j = tid & 3;
            *(u32*)(A6 + m * 136 + 120 + 2 * j) = 0u;
        }
        // epilogue, reference reshape: row=img*4+(n/30), col=(n%30)*4+q
        {
            int n0 = wave * 32 + lr;
            if (n0 < 120) {
                int tt = n0 / 30, cb = (n0 - tt * 30) * 4;
                #pragma unroll
                for (int r = 0; r < 4; ++r) {
                    int m = quad * 4 + r;
                    A6[((m >> 2) * 4 + tt) * 136 + cb + (m & 3)] = (h16)dacc0[r];
                }
            }
            int n1 = wave * 32 + 16 + lr;
            if (n1 < 120) {
                int tt = n1 / 30, cb = (n1 - tt * 30) * 4;
                #pragma unroll
                for (int r = 0; r < 4; ++r) {
                    int m = quad * 4 + r;
                    A6[((m >> 2) * 4 + tt) * 136 + cb + (m & 3)] = (h16)dacc1[r];
                }
            }
        }
    }

    // E iter-0 weight loads + rbfT bounce (global; latency hidden by barrier [7])
    const h16* F6H = (const h16*)(ws + WS_F6H);
    const int wv2 = (wave < 2) ? wave + 4 : wave;   // B-row stays < 96 for all waves
    h8v eb0c = *(const h8v*)(F6H + (wave * 16 + lr) * 128 + quad * 8);
    h8v eb1c = *(const h8v*)(F6H + (wv2 * 16 + lr) * 128 + quad * 8);
    float4 rv = {0.f, 0.f, 0.f, 0.f};
    if (tid < 210) rv = *(const float4*)(ws + WS_RBFT + tid * 4);
    __syncthreads();   // [7] A6 ready; all A5 reads done

    // stage rbfT to LDS (region dead after [7]; read after [8])
    if (tid < 210) *(float4*)(s_rbf + tid * 4) = rv;

    // ======== E: F6+act via MFMA. GEMM [16 x 128] x [128 x 96], depth-2 pipeline ========
    {
        h8v a8c = *(const h8v*)(A6 + lr * 136 + quad * 8);
        float f60 = s_f6b[wave * 16 + lr];
        f4v eacc0 = {f60, f60, f60, f60};
        f4v eacc1 = {};
        const bool w2 = (wave < 2);
        if (w2) {
            int n1 = (wave + 4) * 16 + lr;
            float f61 = (n1 < 84) ? s_f6b[n1] : 0.f;
            eacc1[0] = f61; eacc1[1] = f61; eacc1[2] = f61; eacc1[3] = f61;
        }
        #pragma unroll
        for (int kc = 0; kc < 4; ++kc) {
            h8v eb0n, eb1n, a8n;
            if (kc < 3) {
                eb0n = *(const h8v*)(F6H + (wave * 16 + lr) * 128 + (kc + 1) * 32 + quad * 8);
                eb1n = *(const h8v*)(F6H + (wv2 * 16 + lr) * 128 + (kc + 1) * 32 + quad * 8);
                a8n  = *(const h8v*)(A6 + lr * 136 + (kc + 1) * 32 + quad * 8);
            }
            eacc0 = __builtin_amdgcn_mfma_f32_16x16x32_f16(a8c, eb0c, eacc0, 0, 0, 0);
            if (w2)
                eacc1 = __builtin_amdgcn_mfma_f32_16x16x32_f16(a8c, eb1c, eacc1, 0, 0, 0);
            if (kc < 3) { eb0c = eb0n; eb1c = eb1n; a8c = a8n; }
        }
        {
            int n = wave * 16 + lr;   // 0..63 < 84
            #pragma unroll
            for (int r = 0; r < 4; ++r) {
                int m = quad * 4 + r;
                HB[m * 88 + n] = squash(eacc0[r]);   // HB over dead A5
            }
        }
        if (w2) {
            int n = (wave + 4) * 16 + lr;  // 64..95
            if (n < 84) {
                #pragma unroll
                for (int r = 0; r < 4; ++r) {
                    int m = quad * 4 + r;
                    HB[m * 88 + n] = squash(eacc1[r]);
                }
            }
        }
    }
    __syncthreads();   // [8] HB + rbf ready

    // ======== F: RBF distances (VALU); prototypes from LDS ========
    if (tid < 160) {
        int m = tid / 10, cls = tid - m * 10;
        const float4* hr = (const float4*)(HB + m * 88);
        const float4* pr = (const float4*)(s_rbf + cls * 84);
        float a = 0.f;
        #pragma unroll
        for (int u = 0; u < 21; ++u) {
            float4 hv = hr[u], pv = pr[u];
            float dx = hv.x - pv.x, dy = hv.y - pv.y;
            float dz = hv.z - pv.z, dw = hv.w - pv.w;
            a += dx * dx + dy * dy + dz * dz + dw * dw;
        }
        out[(size_t)blockIdx.x * 160 + tid] = a;
    }
}

extern "C" void kernel_launch(void* const* d_in, const int* in_sizes, int n_in,
                              void* d_out, int out_size, void* d_ws, size_t ws_size,
                              hipStream_t stream) {
    (void)n_in; (void)out_size; (void)ws_size;
    const float* x     = (const float*)d_in[0];
    const float* c1_w  = (const float*)d_in[1];
    const float* c1_b  = (const float*)d_in[2];
    const float* s2_w  = (const float*)d_in[3];
    const float* s2_b  = (const float*)d_in[4];
    const float* c3_w  = (const float*)d_in[5];
    const float* c3_b  = (const float*)d_in[6];
    const float* s4_w  = (const float*)d_in[7];
    const float* s4_b  = (const float*)d_in[8];
    const float* c5_w  = (const float*)d_in[9];
    const float* c5_b  = (const float*)d_in[10];
    const float* f6_w  = (const float*)d_in[11];
    const float* f6_b  = (const float*)d_in[12];
    const float* rbf_w = (const float*)d_in[13];
    float* out = (float*)d_out;
    float* ws  = (float*)d_ws;

    const int B = in_sizes[0] / 1024;   // 8192

    prep_kernel<<<256, 256, 0, stream>>>(c1_w, c1_b, s2_w, s2_b, c3_w, c3_b,
                                         s4_w, s4_b, c5_w, f6_w, rbf_w, ws);
    lenet_kernel<<<B / 4, 256, 0, stream>>>(x, c5_b, f6_b, ws, out);
}

// Round 8
// 132.606 us; speedup vs baseline: 1.4484x; 1.0060x over previous
//
#include <hip/hip_runtime.h>
#include <math.h>

// LeNet-5 fused forward, G=4 images per 256-thread block, 2048 blocks, all-MFMA.
// Round 19: phase F (RBF distances) converted to MFMA GEMM:
//   ||h-p_c||^2 = ||h||^2 - 2 h.p_c + ||p_c||^2
//   - E stores activations as f16 HBH[16][96] (cols 84..95 zeroed)
//   - prep bakes RBFH[16][96] = -2*p^T (f16) and psq[10] = sum(p16^2) (f32)
//   - G: 3 MFMA (h.h^T, B-frag == A-frag, diag = ||h||^2, extracted via __shfl)
//        + 3 MFMA (-2 h.p + psq as accumulator init); wave 0 writes 160 f32
//   - removes: rbfT LDS bounce, f32 HB, 21-iter 160-thread tail loop
// Rest identical to round 18 (passing, spill-free).
typedef _Float16 h16;
typedef h16  h8v __attribute__((ext_vector_type(8)));
typedef h16  h4v __attribute__((ext_vector_type(4)));
typedef h16  h2v __attribute__((ext_vector_type(2)));
typedef float f4v __attribute__((ext_vector_type(4)));
typedef unsigned int u32;

// ws float offsets
#define WS_B1   0       // 6 f32
#define WS_B3   8       // 16 f32
#define WS_KB1  24      // [16][48] f16 (C1 B^T, slot layout) = 768 h16
#define WS_W3H  408     // [6][16][48] f16 (C3 B^T, slot layout) = 4608 h16
#define WS_W5H  2712    // [13][128][32] f16 (C5 B^T, K-packed kg=i*26+r, r<25 valid) = 53248 h16
#define WS_F6H  29336   // [96][128] f16 (F6 B^T, pads 0) = 12288 h16
#define WS_RBFH 35480   // [16][96] f16: -2*p^T, rows>=10 / cols>=84 zero = 1536 h16
#define WS_PSQ  36248   // 10 f32: sum over k of ((f16)p[k][c])^2

// LDS byte offsets (8 barriers)
#define L_B3    0       // 64B
#define L_C5B   64      // 480B (120 f32)
#define L_F6B   544     // 336B (84 f32)
#define L_S2H   880     // 13824B [4][6][16][18] h16 (dead after C)
#define L_A5    880     // 13568B [16][424] h16 (over dead S2H)
#define L_HBH   880     // 3072B [16][96] h16 (over dead A5; written after [7])
#define L_XPAD  14704   // 5184B: 2 imgs x [36][36] h16 (dead after B)
#define L_S4    14704   // 5376B [4][16][42] h16 (over dead XPAD)
#define L_A6    14704   // 4352B [16][136] h16 (over dead S4)
#define L_GUARD 19888   // 192B zero guard (covers out-of-window slot reads)
#define LDS_TOTAL 20080

__device__ const unsigned char MASK16[16] = {7,14,28,56,49,35,15,30,60,57,51,39,27,54,45,63};

// 1.7159*tanh((2/3)x) = 1.7159 - 3.4318/(1 + e^{(4/3)x})
__device__ __forceinline__ float squash(float x) {
    float E = __expf(1.33333333f * x);
    return 1.7159f - 3.4318f * __builtin_amdgcn_rcpf(1.0f + E);
}

// slot c (0..47) -> window (u,v); u=-1 means zero slot
__device__ __forceinline__ void slot_to_uv(int c, int& u, int& v) {
    u = -1; v = 0;
    if (c < 32) {
        int q = c >> 3, j = c & 7;
        if (j < 6)       { u = q;     v = j; }
        else if (q == 2) { u = 4;     v = j - 6; }
        else if (q == 3) { u = 5;     v = j - 6; }
    } else {
        int cc = c - 32, q = cc >> 2, j = cc & 3;
        if (q == 0)      { u = 4;     v = 2 + j; }
        else if (q == 1) { u = 5;     v = 2 + j; }
    }
}

__global__ __launch_bounds__(256) void prep_kernel(
    const float* __restrict__ c1_w, const float* __restrict__ c1_b,
    const float* __restrict__ s2_w, const float* __restrict__ s2_b,
    const float* __restrict__ c3_w, const float* __restrict__ c3_b,
    const float* __restrict__ s4_w, const float* __restrict__ s4_b,
    const float* __restrict__ c5_w, const float* __restrict__ f6_w,
    const float* __restrict__ rbf_w,
    float* __restrict__ ws)
{
    const int gid = blockIdx.x * 256 + threadIdx.x;
    const int gstr = gridDim.x * 256;
    if (gid < 6)  ws[WS_B1 + gid] = s2_w[gid] * c1_b[gid] + s2_b[gid];
    if (gid < 16) ws[WS_B3 + gid] = s4_w[gid] * c3_b[gid] + s4_b[gid];
    h16* KB1 = (h16*)(ws + WS_KB1);
    for (int idx = gid; idx < 768; idx += gstr) {
        int n = idx / 48, c = idx - n * 48;
        int u, v; slot_to_uv(c, u, v);
        float val = 0.f;
        if (n < 6 && u >= 0) {
            float s = 0.f;
            #pragma unroll
            for (int dy = 0; dy < 2; ++dy)
                #pragma unroll
                for (int dx = 0; dx < 2; ++dx) {
                    int ky = u - dy, kx = v - dx;
                    if (ky >= 0 && ky < 5 && kx >= 0 && kx < 5)
                        s += c1_w[(n * 5 + ky) * 5 + kx];
                }
            val = 0.25f * s * s2_w[n];
        }
        KB1[idx] = (h16)val;
    }
    h16* W3H = (h16*)(ws + WS_W3H);
    for (int idx = gid; idx < 4608; idx += gstr) {
        int i = idx / 768, r = idx - i * 768;
        int n = r / 48, c = r - n * 48;
        int u, v; slot_to_uv(c, u, v);
        float val = 0.f;
        if (u >= 0) {
            float s = 0.f;
            #pragma unroll
            for (int dy = 0; dy < 2; ++dy)
                #pragma unroll
                for (int dx = 0; dx < 2; ++dx) {
                    int ky = u - dy, kx = v - dx;
                    if (ky >= 0 && ky < 5 && kx >= 0 && kx < 5)
                        s += c3_w[((n * 6 + i) * 5 + ky) * 5 + kx];
                }
            val = ((MASK16[n] >> i) & 1) ? 0.25f * s4_w[n] * s : 0.f;
        }
        W3H[idx] = (h16)val;
    }
    h16* W5H = (h16*)(ws + WS_W5H);
    for (int idx = gid; idx < 53248; idx += gstr) {
        int kb = idx >> 12, rr = idx & 4095;
        int n = rr >> 5, k = rr & 31;
        int kg = kb * 32 + k;
        int i = kg / 26, r = kg - i * 26;
        float val = (n < 120 && r < 25) ? c5_w[n * 400 + i * 25 + r] : 0.f;
        W5H[idx] = (h16)val;
    }
    h16* F6H = (h16*)(ws + WS_F6H);
    for (int idx = gid; idx < 12288; idx += gstr) {
        int n = idx >> 7, k = idx & 127;
        float val = (n < 84 && k < 120) ? f6_w[n * 120 + k] : 0.f;
        F6H[idx] = (h16)val;
    }
    // RBFH [16 n][96 k] = -2 * p[k][n] (f16); psq[c] = sum_k ((f16)p[k][c])^2
    h16* RBFH = (h16*)(ws + WS_RBFH);
    for (int idx = gid; idx < 1536; idx += gstr) {
        int n = idx / 96, k = idx - n * 96;
        float val = (n < 10 && k < 84) ? -2.f * rbf_w[k * 10 + n] : 0.f;
        RBFH[idx] = (h16)val;
    }
    if (gid < 10) {
        float s = 0.f;
        for (int k = 0; k < 84; ++k) {
            float pv = (float)(h16)rbf_w[k * 10 + gid];
            s += pv * pv;
        }
        ws[WS_PSQ + gid] = s;
    }
}

__global__ __launch_bounds__(256, 8) void lenet_kernel(
    const float* __restrict__ x,
    const float* __restrict__ c5_b, const float* __restrict__ f6_b,
    const float* __restrict__ ws,
    float* __restrict__ out)
{
    __shared__ __align__(16) char smem[LDS_TOTAL];
    float* s_b3  = (float*)(smem + L_B3);
    float* s_c5b = (float*)(smem + L_C5B);
    float* s_f6b = (float*)(smem + L_F6B);
    h16*  XPAD   = (h16*)(smem + L_XPAD);
    h16*  S2H    = (h16*)(smem + L_S2H);
    h16*  S4     = (h16*)(smem + L_S4);
    h16*  A5     = (h16*)(smem + L_A5);
    h16*  A6     = (h16*)(smem + L_A6);
    h16*  HBH    = (h16*)(smem + L_HBH);

    const int tid  = threadIdx.x;
    const int wave = __builtin_amdgcn_readfirstlane(tid >> 6);
    const int lane = tid & 63;
    const int quad = lane >> 4;
    const int lr   = lane & 15;

    // ---- stage consts; zero guard; load B-frags for phase B once (6 VGPRs) ----
    if (tid < 16)  s_b3[tid] = ws[WS_B3 + tid];
    if (tid < 120) s_c5b[tid] = c5_b[tid];
    if (tid < 84)  s_f6b[tid] = f6_b[tid];
    if (tid < 48)  ((u32*)(smem + L_GUARD))[tid] = 0u;
    const float* xb = x + (size_t)blockIdx.x * 4096;
    const h16* KB1 = (const h16*)(ws + WS_KB1);
    h8v w1a = *(const h8v*)(KB1 + lr * 48 + quad * 8);
    h4v w1b = *(const h4v*)(KB1 + lr * 48 + 32 + quad * 4);
    float b1v = ws[WS_B1 + (lr < 6 ? lr : 0)];
    float psqv = ws[WS_PSQ + (lr < 10 ? lr : 0)];

    // phase A stage: load imgs (2s, 2s+1) into XPAD with replicate pad
    auto stageA = [&](int s) {
        #pragma unroll
        for (int k = 0; k < 2; ++k) {
            int idx = tid + k * 256;            // 0..511: interior 2x32x8 float4
            int im = idx >> 8;
            int r  = (idx >> 3) & 31;
            int c4 = idx & 7;
            float4 v = *(const float4*)(xb + (2 * s + im) * 1024 + r * 32 + c4 * 4);
            h2v p0; p0.x = (h16)v.x; p0.y = (h16)v.y;
            h2v p1; p1.x = (h16)v.z; p1.y = (h16)v.w;
            h16* d = XPAD + im * 1296 + (r + 2) * 36 + (4 * c4 + 2);
            *(h2v*)(d)     = p0;
            *(h2v*)(d + 2) = p1;
        }
        #pragma unroll
        for (int k = 0; k < 3; ++k) {
            int e = tid + k * 256;              // 544 halo cells (3 passes)
            if (e < 544) {
                int im = (e >= 272) ? 1 : 0;
                int h = e - 272 * im;
                int u, v;
                if (h < 144) { int q = h / 36; u = (q < 2) ? q : 32 + q; v = h - q * 36; }
                else { int g = h - 144; u = 2 + (g >> 2); int q = g & 3; v = (q < 2) ? q : 32 + q; }
                int sr = min(max(u - 2, 0), 31), sc = min(max(v - 2, 0), 31);
                XPAD[im * 1296 + u * 36 + v] = (h16)xb[(2 * s + im) * 1024 + sr * 32 + sc];
            }
        }
    };

    // phase B stage: C1+S2+act via MFMA im2col, slot-permuted reads (P = 18 dwords)
    auto stageB = [&](int s) {
        const h16* bp = XPAD + (wave >> 1) * 1296 + (wave & 1) * 576 + 2 * lr;
        h16* s2base = S2H + (s * 2 + (wave >> 1)) * 1728 + lr * 288 + (wave & 1) * 144 + quad * 4;
        #pragma unroll
        for (int tt = 0; tt < 8; ++tt) {
            const u32* bq = (const u32*)bp + quad * 18;
            union { u32 u[4]; h8v h; } av;
            av.u[0] = bq[0];  av.u[1] = bq[1];
            av.u[2] = bq[2];  av.u[3] = bq[36];
            f4v acc = {b1v, b1v, b1v, b1v};
            acc = __builtin_amdgcn_mfma_f32_16x16x32_f16(av.h, w1a, acc, 0, 0, 0);
            union { u32 u[2]; h4v h; } av2;
            av2.u[0] = bq[73]; av2.u[1] = bq[74];
            acc = __builtin_amdgcn_mfma_f32_16x16x16f16(av2.h, w1b, acc, 0, 0, 0);
            if (lr < 6) {
                h2v q0; q0.x = (h16)squash(acc[0]); q0.y = (h16)squash(acc[1]);
                h2v q1; q1.x = (h16)squash(acc[2]); q1.y = (h16)squash(acc[3]);
                *(h2v*)(s2base + tt * 18)     = q0;
                *(h2v*)(s2base + tt * 18 + 2) = q1;
            }
            bp += 72;
        }
    };

    stageA(0);
    __syncthreads();   // [1] XPAD(0,1) + consts + guard ready
    stageB(0);
    __syncthreads();   // [2] XPAD(0,1) reads done
    stageA(1);
    __syncthreads();   // [3] XPAD(2,3) ready
    stageB(1);
    __syncthreads();   // [4] S2H ready; XPAD dead

    // ======== C: C3+S4 via MFMA, slot-permuted reads from S2H (P = 9 dwords) ========
    f4v cacc0, cacc1, cacc2;
    const bool w0 = (wave == 0);
    {
        const h16* W3H = (const h16*)(ws + WS_W3H);
        int baseh0, baseh1, baseh2;
        {
            int m0 = wave * 16 + lr;
            int i0 = m0 / 36, p0 = m0 - i0 * 36;
            baseh0 = i0 * 1728 + (2 * (p0 / 6)) * 18 + 2 * (p0 % 6);
            int m1 = (wave + 4) * 16 + lr;
            int i1 = m1 / 36, p1 = m1 - i1 * 36;
            baseh1 = i1 * 1728 + (2 * (p1 / 6)) * 18 + 2 * (p1 % 6);
            int m2 = 128 + lr;   // Mt=8 (wave 0 only)
            int i2 = m2 / 36, p2 = m2 - i2 * 36;
            baseh2 = i2 * 1728 + (2 * (p2 / 6)) * 18 + 2 * (p2 % 6);
        }
        float b3v = s_b3[lr];
        f4v cinit = {b3v, b3v, b3v, b3v};
        cacc0 = cinit; cacc1 = cinit; cacc2 = cinit;
        #pragma unroll
        for (int i = 0; i < 6; ++i) {
            const h16* bbase = W3H + i * 768 + lr * 48;
            h8v w3a = *(const h8v*)(bbase + quad * 8);
            h4v w3b = *(const h4v*)(bbase + 32 + quad * 4);
            {
                const u32* cq = (const u32*)(S2H + baseh0 + i * 288) + quad * 9;
                union { u32 u[4]; h8v h; } av;
                av.u[0] = cq[0];  av.u[1] = cq[1];
                av.u[2] = cq[2];  av.u[3] = cq[18];
                cacc0 = __builtin_amdgcn_mfma_f32_16x16x32_f16(av.h, w3a, cacc0, 0, 0, 0);
                union { u32 u[2]; h4v h; } av2;
                av2.u[0] = cq[37]; av2.u[1] = cq[38];
                cacc0 = __builtin_amdgcn_mfma_f32_16x16x16f16(av2.h, w3b, cacc0, 0, 0, 0);
            }
            {
                const u32* cq = (const u32*)(S2H + baseh1 + i * 288) + quad * 9;
                union { u32 u[4]; h8v h; } av;
                av.u[0] = cq[0];  av.u[1] = cq[1];
                av.u[2] = cq[2];  av.u[3] = cq[18];
                cacc1 = __builtin_amdgcn_mfma_f32_16x16x32_f16(av.h, w3a, cacc1, 0, 0, 0);
                union { u32 u[2]; h4v h; } av2;
                av2.u[0] = cq[37]; av2.u[1] = cq[38];
                cacc1 = __builtin_amdgcn_mfma_f32_16x16x16f16(av2.h, w3b, cacc1, 0, 0, 0);
            }
            if (w0) {
                const u32* cq = (const u32*)(S2H + baseh2 + i * 288) + quad * 9;
                union { u32 u[4]; h8v h; } av;
                av.u[0] = cq[0];  av.u[1] = cq[1];
                av.u[2] = cq[2];  av.u[3] = cq[18];
                cacc2 = __builtin_amdgcn_mfma_f32_16x16x32_f16(av.h, w3a, cacc2, 0, 0, 0);
                union { u32 u[2]; h4v h; } av2;
                av2.u[0] = cq[37]; av2.u[1] = cq[38];
                cacc2 = __builtin_amdgcn_mfma_f32_16x16x16f16(av2.h, w3b, cacc2, 0, 0, 0);
            }
        }
    }

    // D iter-0 weight loads: global (L2), independent of LDS state. Issue NOW so
    // epilogue + barrier [5] + A5 build hide the latency. Only 8 VGPRs in flight.
    const h16* W5H = (const h16*)(ws + WS_W5H);
    h8v bf0c = *(const h8v*)(W5H + (wave * 32 + lr) * 32 + quad * 8);
    h8v bf1c = *(const h8v*)(W5H + (wave * 32 + 16 + lr) * 32 + quad * 8);

    // C epilogue: squash -> S4 (over dead XPAD)
    {
        #pragma unroll
        for (int r = 0; r < 4; ++r) {
            int m = wave * 16 + quad * 4 + r;
            int img = m / 36, pos = m - img * 36;
            S4[img * 672 + lr * 42 + pos] = (h16)squash(cacc0[r]);
        }
        #pragma unroll
        for (int r = 0; r < 4; ++r) {
            int m = (wave + 4) * 16 + quad * 4 + r;
            int img = m / 36, pos = m - img * 36;
            S4[img * 672 + lr * 42 + pos] = (h16)squash(cacc1[r]);
        }
        if (w0) {
            #pragma unroll
            for (int r = 0; r < 4; ++r) {
                int m = 128 + quad * 4 + r;
                int img = m / 36, pos = m - img * 36;
                S4[img * 672 + lr * 42 + pos] = (h16)squash(cacc2[r]);
            }
        }
    }
    __syncthreads();   // [5] S4 ready; all S2H reads done

    // ======== D: C5 via MFMA. GEMM [16 x 416] x [416 x 128], K-packed pitch 26 ========
    // build A5 [16][424] (over dead S2H): thread = (m, i); A5[m][i*26+k] = window val
    {
        int m = tid >> 4, i = tid & 15;
        int img = m >> 2, q = m & 3, qy = q >> 1, qx = q & 1;
        const h16* s4b = S4 + img * 672 + i * 42 + qy * 6 + qx;
        u32* dst = (u32*)(A5 + m * 424 + i * 26);
        #pragma unroll
        for (int w = 0; w < 12; ++w) {
            int k0 = 2 * w, k1 = 2 * w + 1;
            union { h2v h; u32 u; } p;
            p.h.x = s4b[(k0 / 5) * 6 + (k0 % 5)];
            p.h.y = s4b[(k1 / 5) * 6 + (k1 % 5)];
            dst[w] = p.u;
        }
        {
            union { h2v h; u32 u; } p;
            p.h.x = s4b[28];  // k=24 -> (4,4)
            p.h.y = (h16)0.f;
            dst[12] = p.u;
        }
    }
    __syncthreads();   // [6] A5 ready

    {
        // depth-2 rolling pipeline: prefetch iter i+1 while MFMA on iter i.
        h8v af0c = *(const h8v*)(A5 + lr * 424 + quad * 8);
        float c5b0 = s_c5b[wave * 32 + lr];
        float c5b1 = s_c5b[wave * 32 + 16 + lr];   // may over-read into F6B consts; discarded
        f4v dacc0 = {c5b0, c5b0, c5b0, c5b0};
        f4v dacc1 = {c5b1, c5b1, c5b1, c5b1};
        #pragma unroll
        for (int i = 0; i < 13; ++i) {
            h8v bf0n, bf1n, af0n;
            if (i < 12) {
                bf0n = *(const h8v*)(W5H + (i + 1) * 4096 + (wave * 32 + lr) * 32 + quad * 8);
                bf1n = *(const h8v*)(W5H + (i + 1) * 4096 + (wave * 32 + 16 + lr) * 32 + quad * 8);
                af0n = *(const h8v*)(A5 + lr * 424 + (i + 1) * 32 + quad * 8);
            }
            dacc0 = __builtin_amdgcn_mfma_f32_16x16x32_f16(af0c, bf0c, dacc0, 0, 0, 0);
            dacc1 = __builtin_amdgcn_mfma_f32_16x16x32_f16(af0c, bf1c, dacc1, 0, 0, 0);
            if (i < 12) { bf0c = bf0n; bf1c = bf1n; af0c = af0n; }
        }
        // zero pad cols 120..127 of A6 (over dead S4)
        if (tid < 64) {
            int m = tid >> 2, j = tid & 3;
            *(u32*)(A6 + m * 136 + 120 + 2 * j) = 0u;
        }
        // epilogue, reference reshape: row=img*4+(n/30), col=(n%30)*4+q
        {
            int n0 = wave * 32 + lr;
            if (n0 < 120) {
                int tt = n0 / 30, cb = (n0 - tt * 30) * 4;
                #pragma unroll
                for (int r = 0; r < 4; ++r) {
                    int m = quad * 4 + r;
                    A6[((m >> 2) * 4 + tt) * 136 + cb + (m & 3)] = (h16)dacc0[r];
                }
            }
            int n1 = wave * 32 + 16 + lr;
            if (n1 < 120) {
                int tt = n1 / 30, cb = (n1 - tt * 30) * 4;
                #pragma unroll
                for (int r = 0; r < 4; ++r) {
                    int m = quad * 4 + r;
                    A6[((m >> 2) * 4 + tt) * 136 + cb + (m & 3)] = (h16)dacc1[r];
                }
            }
        }
    }

    // E iter-0 weight loads (global; latency hidden by barrier [7])
    const h16* F6H = (const h16*)(ws + WS_F6H);
    const int wv2 = (wave < 2) ? wave + 4 : wave;   // B-row stays < 96 for all waves
    h8v eb0c = *(const h8v*)(F6H + (wave * 16 + lr) * 128 + quad * 8);
    h8v eb1c = *(const h8v*)(F6H + (wv2 * 16 + lr) * 128 + quad * 8);
    __syncthreads();   // [7] A6 ready; all A5 reads done

    // zero-fill HBH cols 84..95 (region over dead A5; rows written by E epilogue)
    if (tid < 96) {
        int m = tid / 6, j = tid - m * 6;
        ((u32*)HBH)[m * 48 + 42 + j] = 0u;
    }

    // ======== E: F6+act via MFMA. GEMM [16 x 128] x [128 x 96], depth-2 pipeline ========
    {
        h8v a8c = *(const h8v*)(A6 + lr * 136 + quad * 8);
        float f60 = s_f6b[wave * 16 + lr];
        f4v eacc0 = {f60, f60, f60, f60};
        f4v eacc1 = {};
        const bool w2 = (wave < 2);
        if (w2) {
            int n1 = (wave + 4) * 16 + lr;
            float f61 = (n1 < 84) ? s_f6b[n1] : 0.f;
            eacc1[0] = f61; eacc1[1] = f61; eacc1[2] = f61; eacc1[3] = f61;
        }
        #pragma unroll
        for (int kc = 0; kc < 4; ++kc) {
            h8v eb0n, eb1n, a8n;
            if (kc < 3) {
                eb0n = *(const h8v*)(F6H + (wave * 16 + lr) * 128 + (kc + 1) * 32 + quad * 8);
                eb1n = *(const h8v*)(F6H + (wv2 * 16 + lr) * 128 + (kc + 1) * 32 + quad * 8);
                a8n  = *(const h8v*)(A6 + lr * 136 + (kc + 1) * 32 + quad * 8);
            }
            eacc0 = __builtin_amdgcn_mfma_f32_16x16x32_f16(a8c, eb0c, eacc0, 0, 0, 0);
            if (w2)
                eacc1 = __builtin_amdgcn_mfma_f32_16x16x32_f16(a8c, eb1c, eacc1, 0, 0, 0);
            if (kc < 3) { eb0c = eb0n; eb1c = eb1n; a8c = a8n; }
        }
        {
            int n = wave * 16 + lr;   // 0..63 < 84
            #pragma unroll
            for (int r = 0; r < 4; ++r) {
                int m = quad * 4 + r;
                HBH[m * 96 + n] = (h16)squash(eacc0[r]);
            }
        }
        if (w2) {
            int n = (wave + 4) * 16 + lr;  // 64..95
            if (n < 84) {
                #pragma unroll
                for (int r = 0; r < 4; ++r) {
                    int m = quad * 4 + r;
                    HBH[m * 96 + n] = (h16)squash(eacc1[r]);
                }
            }
        }
    }
    __syncthreads();   // [8] HBH ready

    // ======== G: RBF distances via MFMA (wave 0 only) ========
    if (w0) {
        const h16* RBFH = (const h16*)(ws + WS_RBFH);
        // issue global B-frag loads first; hh MFMAs below hide their latency
        h8v gb0 = *(const h8v*)(RBFH + lr * 96 + quad * 8);
        h8v gb1 = *(const h8v*)(RBFH + lr * 96 + 32 + quad * 8);
        h8v gb2 = *(const h8v*)(RBFH + lr * 96 + 64 + quad * 8);
        h8v ga0 = *(const h8v*)(HBH + lr * 96 + quad * 8);
        h8v ga1 = *(const h8v*)(HBH + lr * 96 + 32 + quad * 8);
        h8v ga2 = *(const h8v*)(HBH + lr * 96 + 64 + quad * 8);
        // hh[m][n] = sum_k h_m[k] h_n[k]  (B-frag == A-frag)
        f4v hh = {};
        hh = __builtin_amdgcn_mfma_f32_16x16x32_f16(ga0, ga0, hh, 0, 0, 0);
        hh = __builtin_amdgcn_mfma_f32_16x16x32_f16(ga1, ga1, hh, 0, 0, 0);
        hh = __builtin_amdgcn_mfma_f32_16x16x32_f16(ga2, ga2, hh, 0, 0, 0);
        // d2[m][c] = psq[c] + sum_k h_m[k] * (-2 p[k][c])
        f4v d2 = {psqv, psqv, psqv, psqv};
        d2 = __builtin_amdgcn_mfma_f32_16x16x32_f16(ga0, gb0, d2, 0, 0, 0);
        d2 = __builtin_amdgcn_mfma_f32_16x16x32_f16(ga1, gb1, d2, 0, 0, 0);
        d2 = __builtin_amdgcn_mfma_f32_16x16x32_f16(ga2, gb2, d2, 0, 0, 0);
        // out[m][c] = hh[m][m] + d2[m][c]; diag at lane 20*quad+r, reg r
        float* ob = out + (size_t)blockIdx.x * 160;
        #pragma unroll
        for (int r = 0; r < 4; ++r) {
            float hsq = __shfl(hh[r], quad * 20 + r);
            if (lr < 10)
                ob[(quad * 4 + r) * 10 + lr] = hsq + d2[r];
        }
    }
}

extern "C" void kernel_launch(void* const* d_in, const int* in_sizes, int n_in,
                              void* d_out, int out_size, void* d_ws, size_t ws_size,
                              hipStream_t stream) {
    (void)n_in; (void)out_size; (void)ws_size;
    const float* x     = (const float*)d_in[0];
    const float* c1_w  = (const float*)d_in[1];
    const float* c1_b  = (const float*)d_in[2];
    const float* s2_w  = (const float*)d_in[3];
    const float* s2_b  = (const float*)d_in[4];
    const float* c3_w  = (const float*)d_in[5];
    const float* c3_b  = (const float*)d_in[6];
    const float* s4_w  = (const float*)d_in[7];
    const float* s4_b  = (const float*)d_in[8];
    const float* c5_w  = (const float*)d_in[9];
    const float* c5_b  = (const float*)d_in[10];
    const float* f6_w  = (const float*)d_in[11];
    const float* f6_b  = (const float*)d_in[12];
    const float* rbf_w = (const float*)d_in[13];
    float* out = (float*)d_out;
    float* ws  = (float*)d_ws;

    const int B = in_sizes[0] / 1024;   // 8192

    prep_kernel<<<256, 256, 0, stream>>>(c1_w, c1_b, s2_w, s2_b, c3_w, c3_b,
                                         s4_w, s4_b, c5_w, f6_w, rbf_w, ws);
    lenet_kernel<<<B / 4, 256, 0, stream>>>(x, c5_b, f6_b, ws, out);
}

// Round 9
// 130.855 us; speedup vs baseline: 1.4678x; 1.0134x over previous
//
#include <hip/hip_runtime.h>
#include <math.h>

// LeNet-5 fused forward, G=4 images per 256-thread block, 2048 blocks, all-MFMA.
// Round 20: phase D restructured — A5 im2col buffer DELETED.
//   C5 = sum over 25 (r,c) of [16m x 16i] x [16i x 120n] GEMMs (16x16x16 MFMA):
//   - C epilogue stores channel-minor S4T[img][pos][i] (img stride 584 h16, pad 8)
//   - A-frag per (r,c): ONE contiguous ds_read_b64 at an immediate offset
//     (replaces A5 build: 25 ds_read_u16 + 13 ds_write + barrier + 13 ds_read_b128)
//   - W5T[25][128][16] f16 in ws: B-frags are contiguous b64 global loads, rolling depth-2
//   - A6 moved to dead-S2H region (880) -> no S4T-read/A6-write hazard; barrier count 9->7
//   - G: RBFH loads hoisted above barrier [8] (latency hidden under barrier wait)
typedef _Float16 h16;
typedef h16  h8v __attribute__((ext_vector_type(8)));
typedef h16  h4v __attribute__((ext_vector_type(4)));
typedef h16  h2v __attribute__((ext_vector_type(2)));
typedef float f4v __attribute__((ext_vector_type(4)));
typedef unsigned int u32;

// ws float offsets
#define WS_B1   0       // 6 f32
#define WS_B3   8       // 16 f32
#define WS_KB1  24      // [16][48] f16 (C1 B^T, slot layout) = 768 h16
#define WS_W3H  408     // [6][16][48] f16 (C3 B^T, slot layout) = 4608 h16
#define WS_W5T  2712    // [25 rc][128 n][16 i] f16 (C5), n>=120 zero = 51200 h16
#define WS_F6H  28312   // [96][128] f16 (F6 B^T, pads 0) = 12288 h16
#define WS_RBFH 34456   // [16][96] f16: -2*p^T, rows>=10 / cols>=84 zero = 1536 h16
#define WS_PSQ  35224   // 10 f32: sum over k of ((f16)p[k][c])^2

// LDS byte offsets (7 barriers)
#define L_B3    0       // 64B
#define L_C5B   64      // 480B (120 f32)
#define L_F6B   544     // 336B (84 f32)
#define L_S2H   880     // 13824B [4][6][16][18] h16 (dead after C reads, barrier [5])
#define L_A6    880     // 4352B [16][136] h16 (over dead S2H)
#define L_HBH   5232    // 3072B [16][96] h16 (over dead S2H, disjoint from A6)
#define L_XPAD  14704   // 5184B: 2 imgs x [36][36] h16 (dead after B)
#define L_S4T   14704   // 4672B [4 img][36 pos][16 i] h16, img stride 584 (over dead XPAD)
#define L_GUARD 19888   // 192B zero guard (covers out-of-window slot reads)
#define LDS_TOTAL 20080

__device__ const unsigned char MASK16[16] = {7,14,28,56,49,35,15,30,60,57,51,39,27,54,45,63};

// 1.7159*tanh((2/3)x) = 1.7159 - 3.4318/(1 + e^{(4/3)x})
__device__ __forceinline__ float squash(float x) {
    float E = __expf(1.33333333f * x);
    return 1.7159f - 3.4318f * __builtin_amdgcn_rcpf(1.0f + E);
}

// slot c (0..47) -> window (u,v); u=-1 means zero slot
__device__ __forceinline__ void slot_to_uv(int c, int& u, int& v) {
    u = -1; v = 0;
    if (c < 32) {
        int q = c >> 3, j = c & 7;
        if (j < 6)       { u = q;     v = j; }
        else if (q == 2) { u = 4;     v = j - 6; }
        else if (q == 3) { u = 5;     v = j - 6; }
    } else {
        int cc = c - 32, q = cc >> 2, j = cc & 3;
        if (q == 0)      { u = 4;     v = 2 + j; }
        else if (q == 1) { u = 5;     v = 2 + j; }
    }
}

__global__ __launch_bounds__(256) void prep_kernel(
    const float* __restrict__ c1_w, const float* __restrict__ c1_b,
    const float* __restrict__ s2_w, const float* __restrict__ s2_b,
    const float* __restrict__ c3_w, const float* __restrict__ c3_b,
    const float* __restrict__ s4_w, const float* __restrict__ s4_b,
    const float* __restrict__ c5_w, const float* __restrict__ f6_w,
    const float* __restrict__ rbf_w,
    float* __restrict__ ws)
{
    const int gid = blockIdx.x * 256 + threadIdx.x;
    const int gstr = gridDim.x * 256;
    if (gid < 6)  ws[WS_B1 + gid] = s2_w[gid] * c1_b[gid] + s2_b[gid];
    if (gid < 16) ws[WS_B3 + gid] = s4_w[gid] * c3_b[gid] + s4_b[gid];
    h16* KB1 = (h16*)(ws + WS_KB1);
    for (int idx = gid; idx < 768; idx += gstr) {
        int n = idx / 48, c = idx - n * 48;
        int u, v; slot_to_uv(c, u, v);
        float val = 0.f;
        if (n < 6 && u >= 0) {
            float s = 0.f;
            #pragma unroll
            for (int dy = 0; dy < 2; ++dy)
                #pragma unroll
                for (int dx = 0; dx < 2; ++dx) {
                    int ky = u - dy, kx = v - dx;
                    if (ky >= 0 && ky < 5 && kx >= 0 && kx < 5)
                        s += c1_w[(n * 5 + ky) * 5 + kx];
                }
            val = 0.25f * s * s2_w[n];
        }
        KB1[idx] = (h16)val;
    }
    h16* W3H = (h16*)(ws + WS_W3H);
    for (int idx = gid; idx < 4608; idx += gstr) {
        int i = idx / 768, r = idx - i * 768;
        int n = r / 48, c = r - n * 48;
        int u, v; slot_to_uv(c, u, v);
        float val = 0.f;
        if (u >= 0) {
            float s = 0.f;
            #pragma unroll
            for (int dy = 0; dy < 2; ++dy)
                #pragma unroll
                for (int dx = 0; dx < 2; ++dx) {
                    int ky = u - dy, kx = v - dx;
                    if (ky >= 0 && ky < 5 && kx >= 0 && kx < 5)
                        s += c3_w[((n * 6 + i) * 5 + ky) * 5 + kx];
                }
            val = ((MASK16[n] >> i) & 1) ? 0.25f * s4_w[n] * s : 0.f;
        }
        W3H[idx] = (h16)val;
    }
    // W5T [25 rc][128 n][16 i] = c5_w[n][i][r][c]; n>=120 zero
    h16* W5T = (h16*)(ws + WS_W5T);
    for (int idx = gid; idx < 51200; idx += gstr) {
        int rc = idx >> 11;
        int rr = idx & 2047;
        int n = rr >> 4, i = rr & 15;
        float val = (n < 120) ? c5_w[n * 400 + i * 25 + rc] : 0.f;
        W5T[idx] = (h16)val;
    }
    h16* F6H = (h16*)(ws + WS_F6H);
    for (int idx = gid; idx < 12288; idx += gstr) {
        int n = idx >> 7, k = idx & 127;
        float val = (n < 84 && k < 120) ? f6_w[n * 120 + k] : 0.f;
        F6H[idx] = (h16)val;
    }
    // RBFH [16 n][96 k] = -2 * p[k][n] (f16); psq[c] = sum_k ((f16)p[k][c])^2
    h16* RBFH = (h16*)(ws + WS_RBFH);
    for (int idx = gid; idx < 1536; idx += gstr) {
        int n = idx / 96, k = idx - n * 96;
        float val = (n < 10 && k < 84) ? -2.f * rbf_w[k * 10 + n] : 0.f;
        RBFH[idx] = (h16)val;
    }
    if (gid < 10) {
        float s = 0.f;
        for (int k = 0; k < 84; ++k) {
            float pv = (float)(h16)rbf_w[k * 10 + gid];
            s += pv * pv;
        }
        ws[WS_PSQ + gid] = s;
    }
}

__global__ __launch_bounds__(256, 8) void lenet_kernel(
    const float* __restrict__ x,
    const float* __restrict__ c5_b, const float* __restrict__ f6_b,
    const float* __restrict__ ws,
    float* __restrict__ out)
{
    __shared__ __align__(16) char smem[LDS_TOTAL];
    float* s_b3  = (float*)(smem + L_B3);
    float* s_c5b = (float*)(smem + L_C5B);
    float* s_f6b = (float*)(smem + L_F6B);
    h16*  XPAD   = (h16*)(smem + L_XPAD);
    h16*  S2H    = (h16*)(smem + L_S2H);
    h16*  S4T    = (h16*)(smem + L_S4T);
    h16*  A6     = (h16*)(smem + L_A6);
    h16*  HBH    = (h16*)(smem + L_HBH);

    const int tid  = threadIdx.x;
    const int wave = __builtin_amdgcn_readfirstlane(tid >> 6);
    const int lane = tid & 63;
    const int quad = lane >> 4;
    const int lr   = lane & 15;

    // ---- stage consts; zero guard; load B-frags for phase B once (6 VGPRs) ----
    if (tid < 16)  s_b3[tid] = ws[WS_B3 + tid];
    if (tid < 120) s_c5b[tid] = c5_b[tid];
    if (tid < 84)  s_f6b[tid] = f6_b[tid];
    if (tid < 48)  ((u32*)(smem + L_GUARD))[tid] = 0u;
    const float* xb = x + (size_t)blockIdx.x * 4096;
    const h16* KB1 = (const h16*)(ws + WS_KB1);
    h8v w1a = *(const h8v*)(KB1 + lr * 48 + quad * 8);
    h4v w1b = *(const h4v*)(KB1 + lr * 48 + 32 + quad * 4);
    float b1v = ws[WS_B1 + (lr < 6 ? lr : 0)];
    float psqv = ws[WS_PSQ + (lr < 10 ? lr : 0)];

    // phase A stage: load imgs (2s, 2s+1) into XPAD with replicate pad
    auto stageA = [&](int s) {
        #pragma unroll
        for (int k = 0; k < 2; ++k) {
            int idx = tid + k * 256;            // 0..511: interior 2x32x8 float4
            int im = idx >> 8;
            int r  = (idx >> 3) & 31;
            int c4 = idx & 7;
            float4 v = *(const float4*)(xb + (2 * s + im) * 1024 + r * 32 + c4 * 4);
            h2v p0; p0.x = (h16)v.x; p0.y = (h16)v.y;
            h2v p1; p1.x = (h16)v.z; p1.y = (h16)v.w;
            h16* d = XPAD + im * 1296 + (r + 2) * 36 + (4 * c4 + 2);
            *(h2v*)(d)     = p0;
            *(h2v*)(d + 2) = p1;
        }
        #pragma unroll
        for (int k = 0; k < 3; ++k) {
            int e = tid + k * 256;              // 544 halo cells (3 passes)
            if (e < 544) {
                int im = (e >= 272) ? 1 : 0;
                int h = e - 272 * im;
                int u, v;
                if (h < 144) { int q = h / 36; u = (q < 2) ? q : 32 + q; v = h - q * 36; }
                else { int g = h - 144; u = 2 + (g >> 2); int q = g & 3; v = (q < 2) ? q : 32 + q; }
                int sr = min(max(u - 2, 0), 31), sc = min(max(v - 2, 0), 31);
                XPAD[im * 1296 + u * 36 + v] = (h16)xb[(2 * s + im) * 1024 + sr * 32 + sc];
            }
        }
    };

    // phase B stage: C1+S2+act via MFMA im2col, slot-permuted reads (P = 18 dwords)
    auto stageB = [&](int s) {
        const h16* bp = XPAD + (wave >> 1) * 1296 + (wave & 1) * 576 + 2 * lr;
        h16* s2base = S2H + (s * 2 + (wave >> 1)) * 1728 + lr * 288 + (wave & 1) * 144 + quad * 4;
        #pragma unroll
        for (int tt = 0; tt < 8; ++tt) {
            const u32* bq = (const u32*)bp + quad * 18;
            union { u32 u[4]; h8v h; } av;
            av.u[0] = bq[0];  av.u[1] = bq[1];
            av.u[2] = bq[2];  av.u[3] = bq[36];
            f4v acc = {b1v, b1v, b1v, b1v};
            acc = __builtin_amdgcn_mfma_f32_16x16x32_f16(av.h, w1a, acc, 0, 0, 0);
            union { u32 u[2]; h4v h; } av2;
            av2.u[0] = bq[73]; av2.u[1] = bq[74];
            acc = __builtin_amdgcn_mfma_f32_16x16x16f16(av2.h, w1b, acc, 0, 0, 0);
            if (lr < 6) {
                h2v q0; q0.x = (h16)squash(acc[0]); q0.y = (h16)squash(acc[1]);
                h2v q1; q1.x = (h16)squash(acc[2]); q1.y = (h16)squash(acc[3]);
                *(h2v*)(s2base + tt * 18)     = q0;
                *(h2v*)(s2base + tt * 18 + 2) = q1;
            }
            bp += 72;
        }
    };

    stageA(0);
    __syncthreads();   // [1] XPAD(0,1) + consts + guard ready
    stageB(0);
    __syncthreads();   // [2] XPAD(0,1) reads done
    stageA(1);
    __syncthreads();   // [3] XPAD(2,3) ready
    stageB(1);
    __syncthreads();   // [4] S2H ready; XPAD dead

    // ======== C: C3+S4 via MFMA, slot-permuted reads from S2H (P = 9 dwords) ========
    f4v cacc0, cacc1, cacc2;
    const bool w0 = (wave == 0);
    {
        const h16* W3H = (const h16*)(ws + WS_W3H);
        int baseh0, baseh1, baseh2;
        {
            int m0 = wave * 16 + lr;
            int i0 = m0 / 36, p0 = m0 - i0 * 36;
            baseh0 = i0 * 1728 + (2 * (p0 / 6)) * 18 + 2 * (p0 % 6);
            int m1 = (wave + 4) * 16 + lr;
            int i1 = m1 / 36, p1 = m1 - i1 * 36;
            baseh1 = i1 * 1728 + (2 * (p1 / 6)) * 18 + 2 * (p1 % 6);
            int m2 = 128 + lr;   // Mt=8 (wave 0 only)
            int i2 = m2 / 36, p2 = m2 - i2 * 36;
            baseh2 = i2 * 1728 + (2 * (p2 / 6)) * 18 + 2 * (p2 % 6);
        }
        float b3v = s_b3[lr];
        f4v cinit = {b3v, b3v, b3v, b3v};
        cacc0 = cinit; cacc1 = cinit; cacc2 = cinit;
        #pragma unroll
        for (int i = 0; i < 6; ++i) {
            const h16* bbase = W3H + i * 768 + lr * 48;
            h8v w3a = *(const h8v*)(bbase + quad * 8);
            h4v w3b = *(const h4v*)(bbase + 32 + quad * 4);
            {
                const u32* cq = (const u32*)(S2H + baseh0 + i * 288) + quad * 9;
                union { u32 u[4]; h8v h; } av;
                av.u[0] = cq[0];  av.u[1] = cq[1];
                av.u[2] = cq[2];  av.u[3] = cq[18];
                cacc0 = __builtin_amdgcn_mfma_f32_16x16x32_f16(av.h, w3a, cacc0, 0, 0, 0);
                union { u32 u[2]; h4v h; } av2;
                av2.u[0] = cq[37]; av2.u[1] = cq[38];
                cacc0 = __builtin_amdgcn_mfma_f32_16x16x16f16(av2.h, w3b, cacc0, 0, 0, 0);
            }
            {
                const u32* cq = (const u32*)(S2H + baseh1 + i * 288) + quad * 9;
                union { u32 u[4]; h8v h; } av;
                av.u[0] = cq[0];  av.u[1] = cq[1];
                av.u[2] = cq[2];  av.u[3] = cq[18];
                cacc1 = __builtin_amdgcn_mfma_f32_16x16x32_f16(av.h, w3a, cacc1, 0, 0, 0);
                union { u32 u[2]; h4v h; } av2;
                av2.u[0] = cq[37]; av2.u[1] = cq[38];
                cacc1 = __builtin_amdgcn_mfma_f32_16x16x16f16(av2.h, w3b, cacc1, 0, 0, 0);
            }
            if (w0) {
                const u32* cq = (const u32*)(S2H + baseh2 + i * 288) + quad * 9;
                union { u32 u[4]; h8v h; } av;
                av.u[0] = cq[0];  av.u[1] = cq[1];
                av.u[2] = cq[2];  av.u[3] = cq[18];
                cacc2 = __builtin_amdgcn_mfma_f32_16x16x32_f16(av.h, w3a, cacc2, 0, 0, 0);
                union { u32 u[2]; h4v h; } av2;
                av2.u[0] = cq[37]; av2.u[1] = cq[38];
                cacc2 = __builtin_amdgcn_mfma_f32_16x16x16f16(av2.h, w3b, cacc2, 0, 0, 0);
            }
        }
    }

    // D iter-0 B-frag loads: global (L2), independent of LDS state. Issue NOW so
    // epilogue + barrier [5] hide the latency. Only 4 VGPRs in flight.
    const h16* W5T = (const h16*)(ws + WS_W5T);
    const h16* wb0 = W5T + (wave * 32 + lr) * 16 + quad * 4;        // rc stride 2048 h16
    const h16* wb1 = W5T + (wave * 32 + 16 + lr) * 16 + quad * 4;
    h4v b0c = *(const h4v*)(wb0);
    h4v b1c = *(const h4v*)(wb1);

    // C epilogue: squash -> S4T[img][pos][i=lr] (over dead XPAD; img stride 584)
    {
        #pragma unroll
        for (int r = 0; r < 4; ++r) {
            int m = wave * 16 + quad * 4 + r;
            int img = m / 36, pos = m - img * 36;
            S4T[img * 584 + pos * 16 + lr] = (h16)squash(cacc0[r]);
        }
        #pragma unroll
        for (int r = 0; r < 4; ++r) {
            int m = (wave + 4) * 16 + quad * 4 + r;
            int img = m / 36, pos = m - img * 36;
            S4T[img * 584 + pos * 16 + lr] = (h16)squash(cacc1[r]);
        }
        if (w0) {
            #pragma unroll
            for (int r = 0; r < 4; ++r) {
                int m = 128 + quad * 4 + r;
                int img = m / 36, pos = m - img * 36;
                S4T[img * 584 + pos * 16 + lr] = (h16)squash(cacc2[r]);
            }
        }
    }
    __syncthreads();   // [5] S4T ready; all S2H reads done (A6 region free)

    // ======== D: C5 = sum over 25 (r,c) of [16x16]x[16x32/wave] 16x16x16 MFMAs ========
    {
        // A-frag base: lane lr = output row m -> (img, quadrant); quad = k-group (channels)
        int img_ = lr >> 2, q_ = lr & 3;
        const h16* s4b = S4T + img_ * 584 + ((q_ >> 1) * 6 + (q_ & 1)) * 16 + quad * 4;
        // zero pad cols 120..127 of A6 (over dead S2H)
        if (tid < 64) {
            int m = tid >> 2, j = tid & 3;
            *(u32*)(A6 + m * 136 + 120 + 2 * j) = 0u;
        }
        float c5b0 = s_c5b[wave * 32 + lr];
        float c5b1 = s_c5b[wave * 32 + 16 + lr];   // may over-read into F6B consts; discarded
        f4v dacc0 = {c5b0, c5b0, c5b0, c5b0};
        f4v dacc1 = {c5b1, c5b1, c5b1, c5b1};
        h4v a_c = *(const h4v*)(s4b);              // rc=0
        #pragma unroll
        for (int rc = 0; rc < 25; ++rc) {
            h4v a_n, b0n, b1n;
            if (rc < 24) {
                int nr = rc + 1;
                int off = ((nr / 5) * 6 + (nr % 5)) * 16;   // compile-time per unrolled iter
                a_n = *(const h4v*)(s4b + off);
                b0n = *(const h4v*)(wb0 + (rc + 1) * 2048);
                b1n = *(const h4v*)(wb1 + (rc + 1) * 2048);
            }
            dacc0 = __builtin_amdgcn_mfma_f32_16x16x16f16(a_c, b0c, dacc0, 0, 0, 0);
            dacc1 = __builtin_amdgcn_mfma_f32_16x16x16f16(a_c, b1c, dacc1, 0, 0, 0);
            if (rc < 24) { a_c = a_n; b0c = b0n; b1c = b1n; }
        }
        // epilogue, reference reshape: row=img*4+(n/30), col=(n%30)*4+q  (A6 disjoint from S4T)
        {
            int n0 = wave * 32 + lr;
            if (n0 < 120) {
                int tt = n0 / 30, cb = (n0 - tt * 30) * 4;
                #pragma unroll
                for (int r = 0; r < 4; ++r) {
                    int m = quad * 4 + r;
                    A6[((m >> 2) * 4 + tt) * 136 + cb + (m & 3)] = (h16)dacc0[r];
                }
            }
            int n1 = wave * 32 + 16 + lr;
            if (n1 < 120) {
                int tt = n1 / 30, cb = (n1 - tt * 30) * 4;
                #pragma unroll
                for (int r = 0; r < 4; ++r) {
                    int m = quad * 4 + r;
                    A6[((m >> 2) * 4 + tt) * 136 + cb + (m & 3)] = (h16)dacc1[r];
                }
            }
        }
    }

    // E iter-0 weight loads (global; latency hidden by barrier [7])
    const h16* F6H = (const h16*)(ws + WS_F6H);
    const int wv2 = (wave < 2) ? wave + 4 : wave;   // B-row stays < 96 for all waves
    h8v eb0c = *(const h8v*)(F6H + (wave * 16 + lr) * 128 + quad * 8);
    h8v eb1c = *(const h8v*)(F6H + (wv2 * 16 + lr) * 128 + quad * 8);
    __syncthreads();   // [7] A6 ready; all S4T reads done

    // zero-fill HBH cols 84..95 (over dead S2H; rows written by E epilogue)
    if (tid < 96) {
        int m = tid / 6, j = tid - m * 6;
        ((u32*)HBH)[m * 48 + 42 + j] = 0u;
    }

    // ======== E: F6+act via MFMA. GEMM [16 x 128] x [128 x 96], depth-2 pipeline ========
    {
        h8v a8c = *(const h8v*)(A6 + lr * 136 + quad * 8);
        float f60 = s_f6b[wave * 16 + lr];
        f4v eacc0 = {f60, f60, f60, f60};
        f4v eacc1 = {};
        const bool w2 = (wave < 2);
        if (w2) {
            int n1 = (wave + 4) * 16 + lr;
            float f61 = (n1 < 84) ? s_f6b[n1] : 0.f;
            eacc1[0] = f61; eacc1[1] = f61; eacc1[2] = f61; eacc1[3] = f61;
        }
        #pragma unroll
        for (int kc = 0; kc < 4; ++kc) {
            h8v eb0n, eb1n, a8n;
            if (kc < 3) {
                eb0n = *(const h8v*)(F6H + (wave * 16 + lr) * 128 + (kc + 1) * 32 + quad * 8);
                eb1n = *(const h8v*)(F6H + (wv2 * 16 + lr) * 128 + (kc + 1) * 32 + quad * 8);
                a8n  = *(const h8v*)(A6 + lr * 136 + (kc + 1) * 32 + quad * 8);
            }
            eacc0 = __builtin_amdgcn_mfma_f32_16x16x32_f16(a8c, eb0c, eacc0, 0, 0, 0);
            if (w2)
                eacc1 = __builtin_amdgcn_mfma_f32_16x16x32_f16(a8c, eb1c, eacc1, 0, 0, 0);
            if (kc < 3) { eb0c = eb0n; eb1c = eb1n; a8c = a8n; }
        }
        {
            int n = wave * 16 + lr;   // 0..63 < 84
            #pragma unroll
            for (int r = 0; r < 4; ++r) {
                int m = quad * 4 + r;
                HBH[m * 96 + n] = (h16)squash(eacc0[r]);
            }
        }
        if (w2) {
            int n = (wave + 4) * 16 + lr;  // 64..95
            if (n < 84) {
                #pragma unroll
                for (int r = 0; r < 4; ++r) {
                    int m = quad * 4 + r;
                    HBH[m * 96 + n] = (h16)squash(eacc1[r]);
                }
            }
        }
    }

    // G B-frag loads issued BEFORE the barrier: L2 latency hides under barrier wait
    h8v gb0, gb1, gb2;
    if (w0) {
        const h16* RBFH = (const h16*)(ws + WS_RBFH);
        gb0 = *(const h8v*)(RBFH + lr * 96 + quad * 8);
        gb1 = *(const h8v*)(RBFH + lr * 96 + 32 + quad * 8);
        gb2 = *(const h8v*)(RBFH + lr * 96 + 64 + quad * 8);
    }
    __syncthreads();   // [8] HBH ready

    // ======== G: RBF distances via MFMA (wave 0 only) ========
    if (w0) {
        h8v ga0 = *(const h8v*)(HBH + lr * 96 + quad * 8);
        h8v ga1 = *(const h8v*)(HBH + lr * 96 + 32 + quad * 8);
        h8v ga2 = *(const h8v*)(HBH + lr * 96 + 64 + quad * 8);
        // hh[m][n] = sum_k h_m[k] h_n[k]  (B-frag == A-frag)
        f4v hh = {};
        hh = __builtin_amdgcn_mfma_f32_16x16x32_f16(ga0, ga0, hh, 0, 0, 0);
        hh = __builtin_amdgcn_mfma_f32_16x16x32_f16(ga1, ga1, hh, 0, 0, 0);
        hh = __builtin_amdgcn_mfma_f32_16x16x32_f16(ga2, ga2, hh, 0, 0, 0);
        // d2[m][c] = psq[c] + sum_k h_m[k] * (-2 p[k][c])
        f4v d2 = {psqv, psqv, psqv, psqv};
        d2 = __builtin_amdgcn_mfma_f32_16x16x32_f16(ga0, gb0, d2, 0, 0, 0);
        d2 = __builtin_amdgcn_mfma_f32_16x16x32_f16(ga1, gb1, d2, 0, 0, 0);
        d2 = __builtin_amdgcn_mfma_f32_16x16x32_f16(ga2, gb2, d2, 0, 0, 0);
        // out[m][c] = hh[m][m] + d2[m][c]; diag at lane 20*quad+r, reg r
        float* ob = out + (size_t)blockIdx.x * 160;
        #pragma unroll
        for (int r = 0; r < 4; ++r) {
            float hsq = __shfl(hh[r], quad * 20 + r);
            if (lr < 10)
                ob[(quad * 4 + r) * 10 + lr] = hsq + d2[r];
        }
    }
}

extern "C" void kernel_launch(void* const* d_in, const int* in_sizes, int n_in,
                              void* d_out, int out_size, void* d_ws, size_t ws_size,
                              hipStream_t stream) {
    (void)n_in; (void)out_size; (void)ws_size;
    const float* x     = (const float*)d_in[0];
    const float* c1_w  = (const float*)d_in[1];
    const float* c1_b  = (const float*)d_in[2];
    const float* s2_w  = (const float*)d_in[3];
    const float* s2_b  = (const float*)d_in[4];
    const float* c3_w  = (const float*)d_in[5];
    const float* c3_b  = (const float*)d_in[6];
    const float* s4_w  = (const float*)d_in[7];
    const float* s4_b  = (const float*)d_in[8];
    const float* c5_w  = (const float*)d_in[9];
    const float* c5_b  = (const float*)d_in[10];
    const float* f6_w  = (const float*)d_in[11];
    const float* f6_b  = (const float*)d_in[12];
    const float* rbf_w = (const float*)d_in[13];
    float* out = (float*)d_out;
    float* ws  = (float*)d_ws;

    const int B = in_sizes[0] / 1024;   // 8192

    prep_kernel<<<256, 256, 0, stream>>>(c1_w, c1_b, s2_w, s2_b, c3_w, c3_b,
                                         s4_w, s4_b, c5_w, f6_w, rbf_w, ws);
    lenet_kernel<<<B / 4, 256, 0, stream>>>(x, c5_b, f6_b, ws, out);
}